// Round 2
// baseline (582.008 us; speedup 1.0000x reference)
//
#include <hip/hip_runtime.h>
#include <hip/hip_cooperative_groups.h>
#include <math.h>

namespace cg = cooperative_groups;

// DynamicAttention1 — round 14: cooperative fusion, made robust.
// R13 failed with absmax err 3.45 ~= max|ref| -> out stayed zero -> the
// cooperative launch never executed (likely occupancy validation rejected
// grid=768 @ 3 blocks/CU; error code was ignored). Fixes:
//   1. NB computed at runtime from hipOccupancyMaxActiveBlocksPerMultiprocessor
//      (cached); all phases grid-stride / multi-pass generic in NB.
//   2. hipLaunchCooperativeKernel return value CHECKED; on failure fall back
//      permanently to the known-good 4-kernel pipeline (129.6us baseline).
//   3. __threadfence() around grid.sync() for cross-XCD visibility insurance.
//   phases: 1 prep (transposes + keys zero, 2592 vb)
//           2 stageB (keys splitKx2 400 + qh 256 + out_left 256 = 912 vb,
//             alternating fwd/reversed passes to pair heavy keys blocks with
//             light jobs)
//           3 stageC (scgemm 128 + Pgemm 200)
//           4 stageD (softmax + wP -> atomic out, 512 vb)

typedef __attribute__((ext_vector_type(8))) short s16x8;
typedef __attribute__((ext_vector_type(4))) float f32x4;

__device__ __forceinline__ unsigned short f2bf(float f) {
    unsigned int u = __float_as_uint(f);
    return (unsigned short)((u + 0x7fffu + ((u >> 16) & 1u)) >> 16);  // RNE
}

__device__ __forceinline__ s16x8 cvt8(const float* p) {
    float4 u = *(const float4*)p, w = *(const float4*)(p + 4);
    s16x8 o;
    o[0] = (short)f2bf(u.x); o[1] = (short)f2bf(u.y);
    o[2] = (short)f2bf(u.z); o[3] = (short)f2bf(u.w);
    o[4] = (short)f2bf(w.x); o[5] = (short)f2bf(w.y);
    o[6] = (short)f2bf(w.z); o[7] = (short)f2bf(w.w);
    return o;
}

// --------------------------- shared memory union ----------------------------
struct SmemG { unsigned short As[64 * 72]; unsigned short Bs[64 * 72]; };
struct SmemD { float wbuf[200 * 33]; float Bs2[40 * 32]; };
struct SmemT { float tile[32][33]; };
union Smem { SmemG g; SmemD d; SmemT t; };

// ---------------- keys GEMM: A = [src;trg] fp32 (cvt in staging) ------------
__device__ __forceinline__ void gemm64_keys(
    const float* __restrict__ src, const float* __restrict__ trg,
    const unsigned short* __restrict__ BT, float* __restrict__ C,
    int m0, int n0, int kbase, unsigned short* As, unsigned short* Bs) {
    const int t = threadIdx.x;
    const int lane = t & 63, wid = t >> 6;
    const int wm = (wid & 1) * 32, wn = (wid >> 1) * 32;
    const int lr = lane & 15, lq = lane >> 4;
    const int r = t >> 3, c8 = (t & 7) * 8;

    const int ra_row = m0 + r, rb_row = m0 + r + 32;
    const float* arp = (ra_row < 800) ? (src + (size_t)ra_row * 2048)
                                      : (trg + (size_t)(ra_row - 800) * 2048);
    const float* brp = (rb_row < 800) ? (src + (size_t)rb_row * 2048)
                                      : (trg + (size_t)(rb_row - 800) * 2048);

    s16x8 ra0, ra1, rb0, rb1;
#define LDK(kt)                                                            \
    ra0 = cvt8(arp + (kt) + c8);                                           \
    ra1 = cvt8(brp + (kt) + c8);                                           \
    rb0 = *(const s16x8*)(BT + (size_t)(n0 + r)      * 2048 + (kt) + c8);  \
    rb1 = *(const s16x8*)(BT + (size_t)(n0 + r + 32) * 2048 + (kt) + c8);

    f32x4 acc[2][2] = {};
    LDK(kbase);
    for (int it = 0; it < 16; it++) {
        __syncthreads();
        *(s16x8*)&As[r * 72 + c8]        = ra0;
        *(s16x8*)&As[(r + 32) * 72 + c8] = ra1;
        *(s16x8*)&Bs[r * 72 + c8]        = rb0;
        *(s16x8*)&Bs[(r + 32) * 72 + c8] = rb1;
        __syncthreads();
        if (it < 15) { LDK(kbase + (it + 1) * 64); }  // prefetch
#pragma unroll
        for (int s = 0; s < 2; s++) {
            s16x8 a0 = *(const s16x8*)&As[(wm + lr) * 72      + s * 32 + lq * 8];
            s16x8 a1 = *(const s16x8*)&As[(wm + 16 + lr) * 72 + s * 32 + lq * 8];
            s16x8 b0 = *(const s16x8*)&Bs[(wn + lr) * 72      + s * 32 + lq * 8];
            s16x8 b1 = *(const s16x8*)&Bs[(wn + 16 + lr) * 72 + s * 32 + lq * 8];
            acc[0][0] = __builtin_amdgcn_mfma_f32_16x16x32_bf16(a0, b0, acc[0][0], 0, 0, 0);
            acc[0][1] = __builtin_amdgcn_mfma_f32_16x16x32_bf16(a0, b1, acc[0][1], 0, 0, 0);
            acc[1][0] = __builtin_amdgcn_mfma_f32_16x16x32_bf16(a1, b0, acc[1][0], 0, 0, 0);
            acc[1][1] = __builtin_amdgcn_mfma_f32_16x16x32_bf16(a1, b1, acc[1][1], 0, 0, 0);
        }
    }
#undef LDK
#pragma unroll
    for (int i = 0; i < 2; i++)
#pragma unroll
        for (int j = 0; j < 2; j++) {
            const int col = n0 + wn + j * 16 + lr;      // C/D: col=lane&15
            const int row = m0 + wm + i * 16 + lq * 4;  //      row=quad*4+reg
#pragma unroll
            for (int rr = 0; rr < 4; rr++)
                unsafeAtomicAdd(&C[(size_t)(row + rr) * 512 + col], acc[i][j][rr]);
        }
}

// ---------------- P GEMM: P = keys @ WoBot (direct fp32 store) --------------
__device__ __forceinline__ void gemm64_P(
    const float* __restrict__ keys, const unsigned short* __restrict__ wotBot,
    float* __restrict__ P, int m0, int n0, unsigned short* As,
    unsigned short* Bs) {
    const int t = threadIdx.x;
    const int lane = t & 63, wid = t >> 6;
    const int wm = (wid & 1) * 32, wn = (wid >> 1) * 32;
    const int lr = lane & 15, lq = lane >> 4;
    const int r = t >> 3, c8 = (t & 7) * 8;

    s16x8 ra0, ra1, rb0, rb1;
#define LDP(kt)                                                               \
    ra0 = cvt8(keys + (size_t)(m0 + r)      * 512 + (kt) + c8);               \
    ra1 = cvt8(keys + (size_t)(m0 + r + 32) * 512 + (kt) + c8);               \
    rb0 = *(const s16x8*)(wotBot + (size_t)(n0 + r)      * 1024 + (kt) + c8); \
    rb1 = *(const s16x8*)(wotBot + (size_t)(n0 + r + 32) * 1024 + (kt) + c8);

    f32x4 acc[2][2] = {};
    LDP(0);
    for (int it = 0; it < 8; it++) {
        __syncthreads();
        *(s16x8*)&As[r * 72 + c8]        = ra0;
        *(s16x8*)&As[(r + 32) * 72 + c8] = ra1;
        *(s16x8*)&Bs[r * 72 + c8]        = rb0;
        *(s16x8*)&Bs[(r + 32) * 72 + c8] = rb1;
        __syncthreads();
        if (it < 7) { LDP((it + 1) * 64); }  // prefetch
#pragma unroll
        for (int s = 0; s < 2; s++) {
            s16x8 a0 = *(const s16x8*)&As[(wm + lr) * 72      + s * 32 + lq * 8];
            s16x8 a1 = *(const s16x8*)&As[(wm + 16 + lr) * 72 + s * 32 + lq * 8];
            s16x8 b0 = *(const s16x8*)&Bs[(wn + lr) * 72      + s * 32 + lq * 8];
            s16x8 b1 = *(const s16x8*)&Bs[(wn + 16 + lr) * 72 + s * 32 + lq * 8];
            acc[0][0] = __builtin_amdgcn_mfma_f32_16x16x32_bf16(a0, b0, acc[0][0], 0, 0, 0);
            acc[0][1] = __builtin_amdgcn_mfma_f32_16x16x32_bf16(a0, b1, acc[0][1], 0, 0, 0);
            acc[1][0] = __builtin_amdgcn_mfma_f32_16x16x32_bf16(a1, b0, acc[1][0], 0, 0, 0);
            acc[1][1] = __builtin_amdgcn_mfma_f32_16x16x32_bf16(a1, b1, acc[1][1], 0, 0, 0);
        }
    }
#undef LDP
#pragma unroll
    for (int i = 0; i < 2; i++)
#pragma unroll
        for (int j = 0; j < 2; j++) {
            const int col = n0 + wn + j * 16 + lr;
            const int row = m0 + wm + i * 16 + lq * 4;
#pragma unroll
            for (int rr = 0; rr < 4; rr++)
                P[(size_t)(row + rr) * 512 + col] = acc[i][j][rr];
        }
}

// 32x64 tile, 4 waves. A fp32 (cvt in staging). MODE 0: fp32+bias,
// 2: bf16+bias.
template <int MODE>
__device__ __forceinline__ void gemm32(
    const float* __restrict__ A, const unsigned short* __restrict__ BT,
    const float* __restrict__ bias, void* __restrict__ Cv,
    int m0, int n0, int KA, int KB, int N, int kiters,
    unsigned short* As, unsigned short* Bs) {
    const int t = threadIdx.x;
    const int lane = t & 63, wid = t >> 6;
    const int wm = (wid & 1) * 16, wn = (wid >> 1) * 32;
    const int lr = lane & 15, lq = lane >> 4;
    const int r = t >> 3, c8 = (t & 7) * 8;

    s16x8 ra, rb0, rb1;
#define LD32(kt)                                                            \
    ra  = cvt8(A + (size_t)(m0 + r) * KA + (kt) + c8);                      \
    rb0 = *(const s16x8*)(BT + (size_t)(n0 + r)      * KB + (kt) + c8);     \
    rb1 = *(const s16x8*)(BT + (size_t)(n0 + r + 32) * KB + (kt) + c8);

    f32x4 acc[2] = {};
    LD32(0);
    for (int it = 0; it < kiters; it++) {
        __syncthreads();
        *(s16x8*)&As[r * 72 + c8]        = ra;
        *(s16x8*)&Bs[r * 72 + c8]        = rb0;
        *(s16x8*)&Bs[(r + 32) * 72 + c8] = rb1;
        __syncthreads();
        if (it + 1 < kiters) { LD32((it + 1) * 64); }  // prefetch
#pragma unroll
        for (int s = 0; s < 2; s++) {
            s16x8 a0 = *(const s16x8*)&As[(wm + lr) * 72      + s * 32 + lq * 8];
            s16x8 b0 = *(const s16x8*)&Bs[(wn + lr) * 72      + s * 32 + lq * 8];
            s16x8 b1 = *(const s16x8*)&Bs[(wn + 16 + lr) * 72 + s * 32 + lq * 8];
            acc[0] = __builtin_amdgcn_mfma_f32_16x16x32_bf16(a0, b0, acc[0], 0, 0, 0);
            acc[1] = __builtin_amdgcn_mfma_f32_16x16x32_bf16(a0, b1, acc[1], 0, 0, 0);
        }
    }
#undef LD32
#pragma unroll
    for (int j = 0; j < 2; j++) {
        const int col = n0 + wn + j * 16 + lr;
        const int row = m0 + wm + lq * 4;
        const float bv = bias[col];
        if (MODE == 0) {
            float* C = (float*)Cv;
#pragma unroll
            for (int rr = 0; rr < 4; rr++)
                C[(size_t)(row + rr) * N + col] = acc[j][rr] + bv;
        } else {
            unsigned short* C = (unsigned short*)Cv;
#pragma unroll
            for (int rr = 0; rr < 4; rr++)
                C[(size_t)(row + rr) * N + col] = f2bf(acc[j][rr] + bv);
        }
    }
}

// ---------------- phase work units ------------------------------------------
__device__ __forceinline__ void prep_vb(
    int vb, const float* __restrict__ Wq, const float* __restrict__ Ws,
    const float* __restrict__ Wo, unsigned short* __restrict__ wqt,
    unsigned short* __restrict__ wst, unsigned short* __restrict__ wot,
    float* __restrict__ keys, float (*tile)[33]) {
    const int t = threadIdx.x;
    if (vb < 1792) {
        __syncthreads();                 // tile reuse guard across iters
        const int id = vb;
        const float* W; unsigned short* O; int K, tk, tn;
        if (id < 256)       { W = Wq; O = wqt; K = 512;  tk = id >> 4;          tn = id & 15; }
        else if (id < 1280) { W = Ws; O = wst; K = 2048; tk = (id - 256) >> 4;  tn = (id - 256) & 15; }
        else                { W = Wo; O = wot; K = 1024; tk = (id - 1280) >> 4; tn = (id - 1280) & 15; }
        const int row = t >> 3, c4 = (t & 7) * 4;
        float4 v = *(const float4*)(W + (size_t)(tk * 32 + row) * 512 + tn * 32 + c4);
        tile[row][c4 + 0] = v.x; tile[row][c4 + 1] = v.y;
        tile[row][c4 + 2] = v.z; tile[row][c4 + 3] = v.w;
        __syncthreads();
        ushort4 o = make_ushort4(f2bf(tile[c4 + 0][row]), f2bf(tile[c4 + 1][row]),
                                 f2bf(tile[c4 + 2][row]), f2bf(tile[c4 + 3][row]));
        *(ushort4*)(O + (size_t)(tn * 32 + row) * K + tk * 32 + c4) = o;
    } else {
        const int f = ((vb - 1792) * 256 + t) * 4;
        *(float4*)(keys + f) = make_float4(0.f, 0.f, 0.f, 0.f);
    }
}

__device__ __forceinline__ void stageB_vb(
    int vb, const float* __restrict__ query, const float* __restrict__ src,
    const float* __restrict__ trg, const unsigned short* __restrict__ wqt,
    const unsigned short* __restrict__ wst, const unsigned short* __restrict__ wot,
    const float* __restrict__ bq, const float* __restrict__ bo,
    unsigned short* __restrict__ qh, float* __restrict__ keys,
    float* __restrict__ out, unsigned short* As, unsigned short* Bs) {
    if (vb < 400) {
        const int c = vb / 200, rem = vb % 200;
        gemm64_keys(src, trg, wst, keys, (rem >> 3) * 64, (rem & 7) * 64,
                    c * 1024, As, Bs);
    } else if (vb < 656) {
        const int r = vb - 400;
        gemm32<2>(query, wqt, bq, qh, (r >> 3) * 32, (r & 7) * 64, 512, 512,
                  512, 8, As, Bs);
    } else {
        const int r = vb - 656;
        gemm32<0>(query, wot, bo, out, (r >> 3) * 32, (r & 7) * 64, 512, 1024,
                  512, 8, As, Bs);
    }
}

__device__ __forceinline__ void stageC_vb(
    int bid, const unsigned short* __restrict__ qh,
    const float* __restrict__ keys, const unsigned short* __restrict__ wotBot,
    float* __restrict__ sc, float* __restrict__ P,
    unsigned short* As, unsigned short* Bs) {
    const int t = threadIdx.x;

    if (bid >= 128) {                       // ---- Pgemm ----
        const int rem = bid - 128;
        gemm64_P(keys, wotBot, P, (rem >> 3) * 64, (rem & 7) * 64, As, Bs);
        return;
    }

    // ---- scgemm ----
    const int mt = bid >> 2, nt = bid & 3;
    const int m0 = mt * 32, b = mt >> 2, n0 = nt * 64;
    const int lane = t & 63, wid = t >> 6;
    const int wm = (wid & 1) * 16, wn = (wid >> 1) * 32;
    const int lr = lane & 15, lq = lane >> 4;
    const int r = t >> 3, c8 = (t & 7) * 8;

    const int nA = n0 + r, nB = n0 + r + 32;
    int kr0 = (nA < 128) ? (b * 100 + nA) : (800 + b * 100 + (nA - 128));
    int kr1 = (nB < 128) ? (b * 100 + nB) : (800 + b * 100 + (nB - 128));
    kr0 = kr0 > 1599 ? 1599 : kr0;
    kr1 = kr1 > 1599 ? 1599 : kr1;

    s16x8 ra, rb0, rb1;
#define LDSC(kt)                                                    \
    ra  = *(const s16x8*)(qh + (size_t)(m0 + r) * 512 + (kt) + c8); \
    rb0 = cvt8(keys + (size_t)kr0 * 512 + (kt) + c8);               \
    rb1 = cvt8(keys + (size_t)kr1 * 512 + (kt) + c8);

    f32x4 acc[2] = {};
    LDSC(0);
    for (int it = 0; it < 8; it++) {
        __syncthreads();
        *(s16x8*)&As[r * 72 + c8]        = ra;
        *(s16x8*)&Bs[r * 72 + c8]        = rb0;
        *(s16x8*)&Bs[(r + 32) * 72 + c8] = rb1;
        __syncthreads();
        if (it < 7) { LDSC((it + 1) * 64); }
#pragma unroll
        for (int s = 0; s < 2; s++) {
            s16x8 a0 = *(const s16x8*)&As[(wm + lr) * 72      + s * 32 + lq * 8];
            s16x8 b0 = *(const s16x8*)&Bs[(wn + lr) * 72      + s * 32 + lq * 8];
            s16x8 b1 = *(const s16x8*)&Bs[(wn + 16 + lr) * 72 + s * 32 + lq * 8];
            acc[0] = __builtin_amdgcn_mfma_f32_16x16x32_bf16(a0, b0, acc[0], 0, 0, 0);
            acc[1] = __builtin_amdgcn_mfma_f32_16x16x32_bf16(a0, b1, acc[1], 0, 0, 0);
        }
    }
#undef LDSC
#pragma unroll
    for (int j = 0; j < 2; j++) {
        const int col = n0 + wn + j * 16 + lr;
        const int row = m0 + wm + lq * 4;
        const float scale = (col >= 128) ? -(1.0f / 32.0f) : (1.0f / 32.0f);
#pragma unroll
        for (int rr = 0; rr < 4; rr++)
            sc[(size_t)(row + rr) * 256 + col] = acc[j][rr] * scale;
    }
}

__device__ __forceinline__ void stageD_vb(
    int vb, const float* __restrict__ sc, const float* __restrict__ P,
    float* __restrict__ out, float* wbuf, float* Bs) {
    const int t = threadIdx.x;
    const int n0 = (vb & 15) * 32;
    const int b  = (vb >> 4) & 7;
    const int l0 = (vb >> 7) * 32;
    const int wave = t >> 6, lane = t & 63;

    // ---- softmax: each wave handles 8 rows; lane covers cols lane*4..+3 ----
    for (int i = 0; i < 8; i++) {
        const int li = wave * 8 + i;                  // 0..31
        const float4 v = *(const float4*)(
            sc + (size_t)(b * 128 + l0 + li) * 256 + lane * 4);
        const float vv[4] = {v.x, v.y, v.z, v.w};
        const int c0 = lane * 4;
        float mS = -1e30f, mT = -1e30f;
#pragma unroll
        for (int j = 0; j < 4; j++) {
            const int col = c0 + j;
            if (col < 100) mS = fmaxf(mS, vv[j]);
            if (col >= 128 && col < 228) mT = fmaxf(mT, vv[j]);
        }
#pragma unroll
        for (int off = 32; off > 0; off >>= 1) {
            mS = fmaxf(mS, __shfl_xor(mS, off));
            mT = fmaxf(mT, __shfl_xor(mT, off));
        }
        float eS[4], eT[4], sS = 0.f, sT = 0.f;
#pragma unroll
        for (int j = 0; j < 4; j++) {
            const int col = c0 + j;
            eS[j] = (col < 100) ? __expf(vv[j] - mS) : 0.f;
            eT[j] = (col >= 128 && col < 228) ? __expf(vv[j] - mT) : 0.f;
            sS += eS[j]; sT += eT[j];
        }
#pragma unroll
        for (int off = 32; off > 0; off >>= 1) {
            sS += __shfl_xor(sS, off);
            sT += __shfl_xor(sT, off);
        }
        const float iS = 1.f / sS, iT = 1.f / sT;
#pragma unroll
        for (int j = 0; j < 4; j++) {
            const int col = c0 + j;
            if (col < 100) wbuf[col * 33 + li] = eS[j] * iS;
            if (col >= 128 && col < 228)
                wbuf[(100 + col - 128) * 33 + li] = eT[j] * iT;
        }
    }
    __syncthreads();

    // ---- GEMM: acc[l][n] += w[st][l] * (+P_s|-P_t)[st][n] ------------------
    const int tx = t & 7, ty = t >> 3;   // tx: n/4, ty: l
    float rB[5];
    auto loadB = [&](int kbase) {
#pragma unroll
        for (int e = 0; e < 5; e++) {
            const int idx = t + e * 256;
            const int k = idx >> 5, j = idx & 31;
            const int kk = kbase + k;
            rB[e] = (kk < 100)
                ?  P[(size_t)(b * 100 + kk) * 512 + n0 + j]
                : -P[(size_t)(800 + b * 100 + (kk - 100)) * 512 + n0 + j];
        }
    };

    float acc[4] = {};
    loadB(0);
    for (int c5 = 0; c5 < 5; c5++) {
        __syncthreads();
#pragma unroll
        for (int e = 0; e < 5; e++) {
            const int idx = t + e * 256;
            Bs[idx] = rB[e];
        }
        __syncthreads();
        if (c5 < 4) loadB((c5 + 1) * 40);          // prefetch next chunk
#pragma unroll 8
        for (int k = 0; k < 40; k++) {
            const float ar = wbuf[(c5 * 40 + k) * 33 + ty];
            float br[4];
            *(float4*)br = *(const float4*)&Bs[k * 32 + tx * 4];
#pragma unroll
            for (int j = 0; j < 4; j++) acc[j] = fmaf(ar, br[j], acc[j]);
        }
    }

    const float s2 = 0.70710678118654752f;  // 1/sqrt(2)
    const int m = b * 128 + l0 + ty;
#pragma unroll
    for (int j = 0; j < 4; j++)
        unsafeAtomicAdd(&out[(size_t)m * 512 + n0 + tx * 4 + j], acc[j] * s2);
}

// ---------------- fused cooperative kernel ----------------------------------
__global__ __launch_bounds__(256, 3) void k_fused(
    const float* __restrict__ query, const float* __restrict__ src,
    const float* __restrict__ trg, const float* __restrict__ Wq,
    const float* __restrict__ bq, const float* __restrict__ Ws,
    const float* __restrict__ Wo, const float* __restrict__ bo,
    unsigned short* __restrict__ wqt, unsigned short* __restrict__ wst,
    unsigned short* __restrict__ wot, unsigned short* __restrict__ qh,
    float* __restrict__ keys, float* __restrict__ sc,
    float* __restrict__ P, float* __restrict__ out, int NB) {
    cg::grid_group grid = cg::this_grid();
    __shared__ __align__(16) Smem sm;
    const int bid = blockIdx.x;

    // ---- phase 1: weight transposes (1792 vb) + keys zero (800 vb) ---------
    for (int vb = bid; vb < 2592; vb += NB)
        prep_vb(vb, Wq, Ws, Wo, wqt, wst, wot, keys, sm.t.tile);
    __threadfence();
    grid.sync();
    __threadfence();

    // ---- phase 2: keys splitKx2 (400) + qh (256) + out_left (256) ----------
    // alternating fwd/reversed passes pair heavy keys blocks with light jobs
    for (int base = 0, dir = 0; base < 912; base += NB, dir ^= 1) {
        const int vb = base + (dir ? (NB - 1 - bid) : bid);
        if (vb < 912)
            stageB_vb(vb, query, src, trg, wqt, wst, wot, bq, bo, qh, keys,
                      out, sm.g.As, sm.g.Bs);
    }
    __threadfence();
    grid.sync();
    __threadfence();

    // ---- phase 3: scgemm (128) + Pgemm (200) -------------------------------
    for (int vb = bid; vb < 328; vb += NB)
        stageC_vb(vb, qh, keys, wot + 512, sc, P, sm.g.As, sm.g.Bs);
    __threadfence();
    grid.sync();
    __threadfence();

    // ---- phase 4: softmax + wP -> atomic out (512 vb) ----------------------
    for (int vb = bid; vb < 512; vb += NB)
        stageD_vb(vb, sc, P, out, sm.d.wbuf, sm.d.Bs2);
}

// ---------------- fallback kernels (known-good 4-launch pipeline) -----------
__global__ __launch_bounds__(256) void k_prep(
    const float* __restrict__ Wq, const float* __restrict__ Ws,
    const float* __restrict__ Wo,
    unsigned short* __restrict__ WqT, unsigned short* __restrict__ WsT,
    unsigned short* __restrict__ WoT, float* __restrict__ keys) {
    __shared__ float tile[32][33];
    prep_vb(blockIdx.x, Wq, Ws, Wo, WqT, WsT, WoT, keys, tile);
}

__global__ __launch_bounds__(256) void k_stageB(
    const float* __restrict__ query, const float* __restrict__ src,
    const float* __restrict__ trg, const unsigned short* __restrict__ WqT,
    const unsigned short* __restrict__ WsT, const unsigned short* __restrict__ WoT,
    const float* __restrict__ bq, const float* __restrict__ bo,
    unsigned short* __restrict__ qh, float* __restrict__ keys,
    float* __restrict__ out) {
    __shared__ __align__(16) unsigned short As[64 * 72];
    __shared__ __align__(16) unsigned short Bs[64 * 72];
    stageB_vb(blockIdx.x, query, src, trg, WqT, WsT, WoT, bq, bo, qh, keys,
              out, As, Bs);
}

__global__ __launch_bounds__(256) void k_stageC(
    const unsigned short* __restrict__ qh, const float* __restrict__ keys,
    const unsigned short* __restrict__ wotBot, float* __restrict__ sc,
    float* __restrict__ P) {
    __shared__ __align__(16) unsigned short As[64 * 72];
    __shared__ __align__(16) unsigned short Bs[64 * 72];
    stageC_vb(blockIdx.x, qh, keys, wotBot, sc, P, As, Bs);
}

__global__ __launch_bounds__(256) void k_stageD(
    const float* __restrict__ sc, const float* __restrict__ P,
    float* __restrict__ out) {
    __shared__ float wbuf[200 * 33];
    __shared__ float Bs[40 * 32];
    const int vb = blockIdx.x + blockIdx.y * 16 + blockIdx.z * 128;
    stageD_vb(vb, sc, P, out, wbuf, Bs);
}

// ---------------- launch ----------------------------------------------------

extern "C" void kernel_launch(void* const* d_in, const int* in_sizes, int n_in,
                              void* d_out, int out_size, void* d_ws, size_t ws_size,
                              hipStream_t stream) {
    const float* query = (const float*)d_in[0];
    const float* src   = (const float*)d_in[1];
    const float* trg   = (const float*)d_in[2];
    const float* Wq    = (const float*)d_in[3];
    const float* bq    = (const float*)d_in[4];
    const float* Ws    = (const float*)d_in[5];
    const float* Wo    = (const float*)d_in[7];
    const float* bo    = (const float*)d_in[8];
    float* out = (float*)d_out;

    float* keys = (float*)d_ws;               // 1600*512 fp32 (UNBIASED)
    float* sc   = keys + 819200;              // 1024*256 fp32
    float* P    = sc   + 262144;              // 1600*512 fp32 = keys @ WoBot
    unsigned short* qh  = (unsigned short*)(P + 819200);  // 1024x512 bf16
    unsigned short* wqt = qh  + 524288;       // WqT 512x512
    unsigned short* wst = wqt + 262144;       // WsT 512x2048
    unsigned short* wot = wst + 1048576;      // WoT 512x1024

    // ---- NB: runtime occupancy-derived grid size (cached). -1 => fallback.
    static int s_nb = 0;
    if (s_nb == 0) {
        int perCU = 0;
        hipError_t oe = hipOccupancyMaxActiveBlocksPerMultiprocessor(
            &perCU, k_fused, 256, 0);
        if (oe == hipSuccess && perCU > 0) {
            int nCU = 0;
            hipDeviceProp_t prop;
            if (hipGetDeviceProperties(&prop, 0) == hipSuccess)
                nCU = prop.multiProcessorCount;
            if (nCU <= 0) nCU = 256;
            long nb = (long)perCU * nCU;
            s_nb = (int)(nb > 768 ? 768 : nb);
            if (s_nb < 64) s_nb = -1;         // absurdly low -> don't bother
        } else {
            s_nb = -1;
        }
    }

    hipError_t le = hipErrorUnknown;
    if (s_nb > 0) {
        int nbv = s_nb;
        void* args[] = {
            (void*)&query, (void*)&src, (void*)&trg, (void*)&Wq, (void*)&bq,
            (void*)&Ws, (void*)&Wo, (void*)&bo, (void*)&wqt, (void*)&wst,
            (void*)&wot, (void*)&qh, (void*)&keys, (void*)&sc, (void*)&P,
            (void*)&out, (void*)&nbv};
        le = hipLaunchCooperativeKernel(k_fused, dim3(s_nb), dim3(256), args,
                                        0, stream);
        if (le != hipSuccess) s_nb = -1;      // permanently switch to fallback
    }
    if (le != hipSuccess) {
        // known-good 4-kernel pipeline
        k_prep<<<2592, 256, 0, stream>>>(Wq, Ws, Wo, wqt, wst, wot, keys);
        k_stageB<<<912, 256, 0, stream>>>(query, src, trg, wqt, wst, wot, bq,
                                          bo, qh, keys, out);
        k_stageC<<<328, 256, 0, stream>>>(qh, keys, wot + 512, sc, P);
        k_stageD<<<dim3(16, 8, 4), 256, 0, stream>>>(sc, P, out);
    }
}

// Round 3
// 340.181 us; speedup vs baseline: 1.7109x; 1.7109x over previous
//
#include <hip/hip_runtime.h>
#include <hip/hip_cooperative_groups.h>
#include <math.h>

namespace cg = cooperative_groups;

// DynamicAttention1 — round 15: drop explicit __threadfence() around grid.sync.
// R14 was correct but 685us (5x baseline): MfmaUtil 0.32% (= fixed MFMA work),
// FETCH 90MB / WRITE 28MB (+40/+10 vs expected), BW 176 GB/s -> latency-bound
// stall. Theory: per-thread __threadfence() x6 on multi-XCD gfx950 emits
// L2 writeback/invalidate per wave (agent fences must flush non-coherent
// per-XCD L2s) -> ~18K L2 flush ops + full L2 re-fetch per phase.
// grid.sync() already carries release/acquire semantics internally; the
// explicit fences were redundant. Single-variable change for clean A/B.
//   phases: 1 prep (transposes + keys zero, 2592 vb)
//           2 stageB (keys splitKx2 400 + qh 256 + out_left 256 = 912 vb)
//           3 stageC (scgemm 128 + Pgemm 200)
//           4 stageD (softmax + wP -> atomic out, 512 vb)
// Fallback to known-good 4-kernel pipeline if coop launch fails.

typedef __attribute__((ext_vector_type(8))) short s16x8;
typedef __attribute__((ext_vector_type(4))) float f32x4;

__device__ __forceinline__ unsigned short f2bf(float f) {
    unsigned int u = __float_as_uint(f);
    return (unsigned short)((u + 0x7fffu + ((u >> 16) & 1u)) >> 16);  // RNE
}

__device__ __forceinline__ s16x8 cvt8(const float* p) {
    float4 u = *(const float4*)p, w = *(const float4*)(p + 4);
    s16x8 o;
    o[0] = (short)f2bf(u.x); o[1] = (short)f2bf(u.y);
    o[2] = (short)f2bf(u.z); o[3] = (short)f2bf(u.w);
    o[4] = (short)f2bf(w.x); o[5] = (short)f2bf(w.y);
    o[6] = (short)f2bf(w.z); o[7] = (short)f2bf(w.w);
    return o;
}

// --------------------------- shared memory union ----------------------------
struct SmemG { unsigned short As[64 * 72]; unsigned short Bs[64 * 72]; };
struct SmemD { float wbuf[200 * 33]; float Bs2[40 * 32]; };
struct SmemT { float tile[32][33]; };
union Smem { SmemG g; SmemD d; SmemT t; };

// ---------------- keys GEMM: A = [src;trg] fp32 (cvt in staging) ------------
__device__ __forceinline__ void gemm64_keys(
    const float* __restrict__ src, const float* __restrict__ trg,
    const unsigned short* __restrict__ BT, float* __restrict__ C,
    int m0, int n0, int kbase, unsigned short* As, unsigned short* Bs) {
    const int t = threadIdx.x;
    const int lane = t & 63, wid = t >> 6;
    const int wm = (wid & 1) * 32, wn = (wid >> 1) * 32;
    const int lr = lane & 15, lq = lane >> 4;
    const int r = t >> 3, c8 = (t & 7) * 8;

    const int ra_row = m0 + r, rb_row = m0 + r + 32;
    const float* arp = (ra_row < 800) ? (src + (size_t)ra_row * 2048)
                                      : (trg + (size_t)(ra_row - 800) * 2048);
    const float* brp = (rb_row < 800) ? (src + (size_t)rb_row * 2048)
                                      : (trg + (size_t)(rb_row - 800) * 2048);

    s16x8 ra0, ra1, rb0, rb1;
#define LDK(kt)                                                            \
    ra0 = cvt8(arp + (kt) + c8);                                           \
    ra1 = cvt8(brp + (kt) + c8);                                           \
    rb0 = *(const s16x8*)(BT + (size_t)(n0 + r)      * 2048 + (kt) + c8);  \
    rb1 = *(const s16x8*)(BT + (size_t)(n0 + r + 32) * 2048 + (kt) + c8);

    f32x4 acc[2][2] = {};
    LDK(kbase);
    for (int it = 0; it < 16; it++) {
        __syncthreads();
        *(s16x8*)&As[r * 72 + c8]        = ra0;
        *(s16x8*)&As[(r + 32) * 72 + c8] = ra1;
        *(s16x8*)&Bs[r * 72 + c8]        = rb0;
        *(s16x8*)&Bs[(r + 32) * 72 + c8] = rb1;
        __syncthreads();
        if (it < 15) { LDK(kbase + (it + 1) * 64); }  // prefetch
#pragma unroll
        for (int s = 0; s < 2; s++) {
            s16x8 a0 = *(const s16x8*)&As[(wm + lr) * 72      + s * 32 + lq * 8];
            s16x8 a1 = *(const s16x8*)&As[(wm + 16 + lr) * 72 + s * 32 + lq * 8];
            s16x8 b0 = *(const s16x8*)&Bs[(wn + lr) * 72      + s * 32 + lq * 8];
            s16x8 b1 = *(const s16x8*)&Bs[(wn + 16 + lr) * 72 + s * 32 + lq * 8];
            acc[0][0] = __builtin_amdgcn_mfma_f32_16x16x32_bf16(a0, b0, acc[0][0], 0, 0, 0);
            acc[0][1] = __builtin_amdgcn_mfma_f32_16x16x32_bf16(a0, b1, acc[0][1], 0, 0, 0);
            acc[1][0] = __builtin_amdgcn_mfma_f32_16x16x32_bf16(a1, b0, acc[1][0], 0, 0, 0);
            acc[1][1] = __builtin_amdgcn_mfma_f32_16x16x32_bf16(a1, b1, acc[1][1], 0, 0, 0);
        }
    }
#undef LDK
#pragma unroll
    for (int i = 0; i < 2; i++)
#pragma unroll
        for (int j = 0; j < 2; j++) {
            const int col = n0 + wn + j * 16 + lr;      // C/D: col=lane&15
            const int row = m0 + wm + i * 16 + lq * 4;  //      row=quad*4+reg
#pragma unroll
            for (int rr = 0; rr < 4; rr++)
                unsafeAtomicAdd(&C[(size_t)(row + rr) * 512 + col], acc[i][j][rr]);
        }
}

// ---------------- P GEMM: P = keys @ WoBot (direct fp32 store) --------------
__device__ __forceinline__ void gemm64_P(
    const float* __restrict__ keys, const unsigned short* __restrict__ wotBot,
    float* __restrict__ P, int m0, int n0, unsigned short* As,
    unsigned short* Bs) {
    const int t = threadIdx.x;
    const int lane = t & 63, wid = t >> 6;
    const int wm = (wid & 1) * 32, wn = (wid >> 1) * 32;
    const int lr = lane & 15, lq = lane >> 4;
    const int r = t >> 3, c8 = (t & 7) * 8;

    s16x8 ra0, ra1, rb0, rb1;
#define LDP(kt)                                                               \
    ra0 = cvt8(keys + (size_t)(m0 + r)      * 512 + (kt) + c8);               \
    ra1 = cvt8(keys + (size_t)(m0 + r + 32) * 512 + (kt) + c8);               \
    rb0 = *(const s16x8*)(wotBot + (size_t)(n0 + r)      * 1024 + (kt) + c8); \
    rb1 = *(const s16x8*)(wotBot + (size_t)(n0 + r + 32) * 1024 + (kt) + c8);

    f32x4 acc[2][2] = {};
    LDP(0);
    for (int it = 0; it < 8; it++) {
        __syncthreads();
        *(s16x8*)&As[r * 72 + c8]        = ra0;
        *(s16x8*)&As[(r + 32) * 72 + c8] = ra1;
        *(s16x8*)&Bs[r * 72 + c8]        = rb0;
        *(s16x8*)&Bs[(r + 32) * 72 + c8] = rb1;
        __syncthreads();
        if (it < 7) { LDP((it + 1) * 64); }  // prefetch
#pragma unroll
        for (int s = 0; s < 2; s++) {
            s16x8 a0 = *(const s16x8*)&As[(wm + lr) * 72      + s * 32 + lq * 8];
            s16x8 a1 = *(const s16x8*)&As[(wm + 16 + lr) * 72 + s * 32 + lq * 8];
            s16x8 b0 = *(const s16x8*)&Bs[(wn + lr) * 72      + s * 32 + lq * 8];
            s16x8 b1 = *(const s16x8*)&Bs[(wn + 16 + lr) * 72 + s * 32 + lq * 8];
            acc[0][0] = __builtin_amdgcn_mfma_f32_16x16x32_bf16(a0, b0, acc[0][0], 0, 0, 0);
            acc[0][1] = __builtin_amdgcn_mfma_f32_16x16x32_bf16(a0, b1, acc[0][1], 0, 0, 0);
            acc[1][0] = __builtin_amdgcn_mfma_f32_16x16x32_bf16(a1, b0, acc[1][0], 0, 0, 0);
            acc[1][1] = __builtin_amdgcn_mfma_f32_16x16x32_bf16(a1, b1, acc[1][1], 0, 0, 0);
        }
    }
#undef LDP
#pragma unroll
    for (int i = 0; i < 2; i++)
#pragma unroll
        for (int j = 0; j < 2; j++) {
            const int col = n0 + wn + j * 16 + lr;
            const int row = m0 + wm + i * 16 + lq * 4;
#pragma unroll
            for (int rr = 0; rr < 4; rr++)
                P[(size_t)(row + rr) * 512 + col] = acc[i][j][rr];
        }
}

// 32x64 tile, 4 waves. A fp32 (cvt in staging). MODE 0: fp32+bias,
// 2: bf16+bias.
template <int MODE>
__device__ __forceinline__ void gemm32(
    const float* __restrict__ A, const unsigned short* __restrict__ BT,
    const float* __restrict__ bias, void* __restrict__ Cv,
    int m0, int n0, int KA, int KB, int N, int kiters,
    unsigned short* As, unsigned short* Bs) {
    const int t = threadIdx.x;
    const int lane = t & 63, wid = t >> 6;
    const int wm = (wid & 1) * 16, wn = (wid >> 1) * 32;
    const int lr = lane & 15, lq = lane >> 4;
    const int r = t >> 3, c8 = (t & 7) * 8;

    s16x8 ra, rb0, rb1;
#define LD32(kt)                                                            \
    ra  = cvt8(A + (size_t)(m0 + r) * KA + (kt) + c8);                      \
    rb0 = *(const s16x8*)(BT + (size_t)(n0 + r)      * KB + (kt) + c8);     \
    rb1 = *(const s16x8*)(BT + (size_t)(n0 + r + 32) * KB + (kt) + c8);

    f32x4 acc[2] = {};
    LD32(0);
    for (int it = 0; it < kiters; it++) {
        __syncthreads();
        *(s16x8*)&As[r * 72 + c8]        = ra;
        *(s16x8*)&Bs[r * 72 + c8]        = rb0;
        *(s16x8*)&Bs[(r + 32) * 72 + c8] = rb1;
        __syncthreads();
        if (it + 1 < kiters) { LD32((it + 1) * 64); }  // prefetch
#pragma unroll
        for (int s = 0; s < 2; s++) {
            s16x8 a0 = *(const s16x8*)&As[(wm + lr) * 72      + s * 32 + lq * 8];
            s16x8 b0 = *(const s16x8*)&Bs[(wn + lr) * 72      + s * 32 + lq * 8];
            s16x8 b1 = *(const s16x8*)&Bs[(wn + 16 + lr) * 72 + s * 32 + lq * 8];
            acc[0] = __builtin_amdgcn_mfma_f32_16x16x32_bf16(a0, b0, acc[0], 0, 0, 0);
            acc[1] = __builtin_amdgcn_mfma_f32_16x16x32_bf16(a0, b1, acc[1], 0, 0, 0);
        }
    }
#undef LD32
#pragma unroll
    for (int j = 0; j < 2; j++) {
        const int col = n0 + wn + j * 16 + lr;
        const int row = m0 + wm + lq * 4;
        const float bv = bias[col];
        if (MODE == 0) {
            float* C = (float*)Cv;
#pragma unroll
            for (int rr = 0; rr < 4; rr++)
                C[(size_t)(row + rr) * N + col] = acc[j][rr] + bv;
        } else {
            unsigned short* C = (unsigned short*)Cv;
#pragma unroll
            for (int rr = 0; rr < 4; rr++)
                C[(size_t)(row + rr) * N + col] = f2bf(acc[j][rr] + bv);
        }
    }
}

// ---------------- phase work units ------------------------------------------
__device__ __forceinline__ void prep_vb(
    int vb, const float* __restrict__ Wq, const float* __restrict__ Ws,
    const float* __restrict__ Wo, unsigned short* __restrict__ wqt,
    unsigned short* __restrict__ wst, unsigned short* __restrict__ wot,
    float* __restrict__ keys, float (*tile)[33]) {
    const int t = threadIdx.x;
    if (vb < 1792) {
        __syncthreads();                 // tile reuse guard across iters
        const int id = vb;
        const float* W; unsigned short* O; int K, tk, tn;
        if (id < 256)       { W = Wq; O = wqt; K = 512;  tk = id >> 4;          tn = id & 15; }
        else if (id < 1280) { W = Ws; O = wst; K = 2048; tk = (id - 256) >> 4;  tn = (id - 256) & 15; }
        else                { W = Wo; O = wot; K = 1024; tk = (id - 1280) >> 4; tn = (id - 1280) & 15; }
        const int row = t >> 3, c4 = (t & 7) * 4;
        float4 v = *(const float4*)(W + (size_t)(tk * 32 + row) * 512 + tn * 32 + c4);
        tile[row][c4 + 0] = v.x; tile[row][c4 + 1] = v.y;
        tile[row][c4 + 2] = v.z; tile[row][c4 + 3] = v.w;
        __syncthreads();
        ushort4 o = make_ushort4(f2bf(tile[c4 + 0][row]), f2bf(tile[c4 + 1][row]),
                                 f2bf(tile[c4 + 2][row]), f2bf(tile[c4 + 3][row]));
        *(ushort4*)(O + (size_t)(tn * 32 + row) * K + tk * 32 + c4) = o;
    } else {
        const int f = ((vb - 1792) * 256 + t) * 4;
        *(float4*)(keys + f) = make_float4(0.f, 0.f, 0.f, 0.f);
    }
}

__device__ __forceinline__ void stageB_vb(
    int vb, const float* __restrict__ query, const float* __restrict__ src,
    const float* __restrict__ trg, const unsigned short* __restrict__ wqt,
    const unsigned short* __restrict__ wst, const unsigned short* __restrict__ wot,
    const float* __restrict__ bq, const float* __restrict__ bo,
    unsigned short* __restrict__ qh, float* __restrict__ keys,
    float* __restrict__ out, unsigned short* As, unsigned short* Bs) {
    if (vb < 400) {
        const int c = vb / 200, rem = vb % 200;
        gemm64_keys(src, trg, wst, keys, (rem >> 3) * 64, (rem & 7) * 64,
                    c * 1024, As, Bs);
    } else if (vb < 656) {
        const int r = vb - 400;
        gemm32<2>(query, wqt, bq, qh, (r >> 3) * 32, (r & 7) * 64, 512, 512,
                  512, 8, As, Bs);
    } else {
        const int r = vb - 656;
        gemm32<0>(query, wot, bo, out, (r >> 3) * 32, (r & 7) * 64, 512, 1024,
                  512, 8, As, Bs);
    }
}

__device__ __forceinline__ void stageC_vb(
    int bid, const unsigned short* __restrict__ qh,
    const float* __restrict__ keys, const unsigned short* __restrict__ wotBot,
    float* __restrict__ sc, float* __restrict__ P,
    unsigned short* As, unsigned short* Bs) {
    const int t = threadIdx.x;

    if (bid >= 128) {                       // ---- Pgemm ----
        const int rem = bid - 128;
        gemm64_P(keys, wotBot, P, (rem >> 3) * 64, (rem & 7) * 64, As, Bs);
        return;
    }

    // ---- scgemm ----
    const int mt = bid >> 2, nt = bid & 3;
    const int m0 = mt * 32, b = mt >> 2, n0 = nt * 64;
    const int lane = t & 63, wid = t >> 6;
    const int wm = (wid & 1) * 16, wn = (wid >> 1) * 32;
    const int lr = lane & 15, lq = lane >> 4;
    const int r = t >> 3, c8 = (t & 7) * 8;

    const int nA = n0 + r, nB = n0 + r + 32;
    int kr0 = (nA < 128) ? (b * 100 + nA) : (800 + b * 100 + (nA - 128));
    int kr1 = (nB < 128) ? (b * 100 + nB) : (800 + b * 100 + (nB - 128));
    kr0 = kr0 > 1599 ? 1599 : kr0;
    kr1 = kr1 > 1599 ? 1599 : kr1;

    s16x8 ra, rb0, rb1;
#define LDSC(kt)                                                    \
    ra  = *(const s16x8*)(qh + (size_t)(m0 + r) * 512 + (kt) + c8); \
    rb0 = cvt8(keys + (size_t)kr0 * 512 + (kt) + c8);               \
    rb1 = cvt8(keys + (size_t)kr1 * 512 + (kt) + c8);

    f32x4 acc[2] = {};
    LDSC(0);
    for (int it = 0; it < 8; it++) {
        __syncthreads();
        *(s16x8*)&As[r * 72 + c8]        = ra;
        *(s16x8*)&Bs[r * 72 + c8]        = rb0;
        *(s16x8*)&Bs[(r + 32) * 72 + c8] = rb1;
        __syncthreads();
        if (it < 7) { LDSC((it + 1) * 64); }
#pragma unroll
        for (int s = 0; s < 2; s++) {
            s16x8 a0 = *(const s16x8*)&As[(wm + lr) * 72      + s * 32 + lq * 8];
            s16x8 b0 = *(const s16x8*)&Bs[(wn + lr) * 72      + s * 32 + lq * 8];
            s16x8 b1 = *(const s16x8*)&Bs[(wn + 16 + lr) * 72 + s * 32 + lq * 8];
            acc[0] = __builtin_amdgcn_mfma_f32_16x16x32_bf16(a0, b0, acc[0], 0, 0, 0);
            acc[1] = __builtin_amdgcn_mfma_f32_16x16x32_bf16(a0, b1, acc[1], 0, 0, 0);
        }
    }
#undef LDSC
#pragma unroll
    for (int j = 0; j < 2; j++) {
        const int col = n0 + wn + j * 16 + lr;
        const int row = m0 + wm + lq * 4;
        const float scale = (col >= 128) ? -(1.0f / 32.0f) : (1.0f / 32.0f);
#pragma unroll
        for (int rr = 0; rr < 4; rr++)
            sc[(size_t)(row + rr) * 256 + col] = acc[j][rr] * scale;
    }
}

__device__ __forceinline__ void stageD_vb(
    int vb, const float* __restrict__ sc, const float* __restrict__ P,
    float* __restrict__ out, float* wbuf, float* Bs) {
    const int t = threadIdx.x;
    const int n0 = (vb & 15) * 32;
    const int b  = (vb >> 4) & 7;
    const int l0 = (vb >> 7) * 32;
    const int wave = t >> 6, lane = t & 63;

    // ---- softmax: each wave handles 8 rows; lane covers cols lane*4..+3 ----
    for (int i = 0; i < 8; i++) {
        const int li = wave * 8 + i;                  // 0..31
        const float4 v = *(const float4*)(
            sc + (size_t)(b * 128 + l0 + li) * 256 + lane * 4);
        const float vv[4] = {v.x, v.y, v.z, v.w};
        const int c0 = lane * 4;
        float mS = -1e30f, mT = -1e30f;
#pragma unroll
        for (int j = 0; j < 4; j++) {
            const int col = c0 + j;
            if (col < 100) mS = fmaxf(mS, vv[j]);
            if (col >= 128 && col < 228) mT = fmaxf(mT, vv[j]);
        }
#pragma unroll
        for (int off = 32; off > 0; off >>= 1) {
            mS = fmaxf(mS, __shfl_xor(mS, off));
            mT = fmaxf(mT, __shfl_xor(mT, off));
        }
        float eS[4], eT[4], sS = 0.f, sT = 0.f;
#pragma unroll
        for (int j = 0; j < 4; j++) {
            const int col = c0 + j;
            eS[j] = (col < 100) ? __expf(vv[j] - mS) : 0.f;
            eT[j] = (col >= 128 && col < 228) ? __expf(vv[j] - mT) : 0.f;
            sS += eS[j]; sT += eT[j];
        }
#pragma unroll
        for (int off = 32; off > 0; off >>= 1) {
            sS += __shfl_xor(sS, off);
            sT += __shfl_xor(sT, off);
        }
        const float iS = 1.f / sS, iT = 1.f / sT;
#pragma unroll
        for (int j = 0; j < 4; j++) {
            const int col = c0 + j;
            if (col < 100) wbuf[col * 33 + li] = eS[j] * iS;
            if (col >= 128 && col < 228)
                wbuf[(100 + col - 128) * 33 + li] = eT[j] * iT;
        }
    }
    __syncthreads();

    // ---- GEMM: acc[l][n] += w[st][l] * (+P_s|-P_t)[st][n] ------------------
    const int tx = t & 7, ty = t >> 3;   // tx: n/4, ty: l
    float rB[5];
    auto loadB = [&](int kbase) {
#pragma unroll
        for (int e = 0; e < 5; e++) {
            const int idx = t + e * 256;
            const int k = idx >> 5, j = idx & 31;
            const int kk = kbase + k;
            rB[e] = (kk < 100)
                ?  P[(size_t)(b * 100 + kk) * 512 + n0 + j]
                : -P[(size_t)(800 + b * 100 + (kk - 100)) * 512 + n0 + j];
        }
    };

    float acc[4] = {};
    loadB(0);
    for (int c5 = 0; c5 < 5; c5++) {
        __syncthreads();
#pragma unroll
        for (int e = 0; e < 5; e++) {
            const int idx = t + e * 256;
            Bs[idx] = rB[e];
        }
        __syncthreads();
        if (c5 < 4) loadB((c5 + 1) * 40);          // prefetch next chunk
#pragma unroll 8
        for (int k = 0; k < 40; k++) {
            const float ar = wbuf[(c5 * 40 + k) * 33 + ty];
            float br[4];
            *(float4*)br = *(const float4*)&Bs[k * 32 + tx * 4];
#pragma unroll
            for (int j = 0; j < 4; j++) acc[j] = fmaf(ar, br[j], acc[j]);
        }
    }

    const float s2 = 0.70710678118654752f;  // 1/sqrt(2)
    const int m = b * 128 + l0 + ty;
#pragma unroll
    for (int j = 0; j < 4; j++)
        unsafeAtomicAdd(&out[(size_t)m * 512 + n0 + tx * 4 + j], acc[j] * s2);
}

// ---------------- fused cooperative kernel ----------------------------------
__global__ __launch_bounds__(256, 3) void k_fused(
    const float* __restrict__ query, const float* __restrict__ src,
    const float* __restrict__ trg, const float* __restrict__ Wq,
    const float* __restrict__ bq, const float* __restrict__ Ws,
    const float* __restrict__ Wo, const float* __restrict__ bo,
    unsigned short* __restrict__ wqt, unsigned short* __restrict__ wst,
    unsigned short* __restrict__ wot, unsigned short* __restrict__ qh,
    float* __restrict__ keys, float* __restrict__ sc,
    float* __restrict__ P, float* __restrict__ out, int NB) {
    cg::grid_group grid = cg::this_grid();
    __shared__ __align__(16) Smem sm;
    const int bid = blockIdx.x;

    // ---- phase 1: weight transposes (1792 vb) + keys zero (800 vb) ---------
    for (int vb = bid; vb < 2592; vb += NB)
        prep_vb(vb, Wq, Ws, Wo, wqt, wst, wot, keys, sm.t.tile);
    grid.sync();

    // ---- phase 2: keys splitKx2 (400) + qh (256) + out_left (256) ----------
    // alternating fwd/reversed passes pair heavy keys blocks with light jobs
    for (int base = 0, dir = 0; base < 912; base += NB, dir ^= 1) {
        const int vb = base + (dir ? (NB - 1 - bid) : bid);
        if (vb < 912)
            stageB_vb(vb, query, src, trg, wqt, wst, wot, bq, bo, qh, keys,
                      out, sm.g.As, sm.g.Bs);
    }
    grid.sync();

    // ---- phase 3: scgemm (128) + Pgemm (200) -------------------------------
    for (int vb = bid; vb < 328; vb += NB)
        stageC_vb(vb, qh, keys, wot + 512, sc, P, sm.g.As, sm.g.Bs);
    grid.sync();

    // ---- phase 4: softmax + wP -> atomic out (512 vb) ----------------------
    for (int vb = bid; vb < 512; vb += NB)
        stageD_vb(vb, sc, P, out, sm.d.wbuf, sm.d.Bs2);
}

// ---------------- fallback kernels (known-good 4-launch pipeline) -----------
__global__ __launch_bounds__(256) void k_prep(
    const float* __restrict__ Wq, const float* __restrict__ Ws,
    const float* __restrict__ Wo,
    unsigned short* __restrict__ WqT, unsigned short* __restrict__ WsT,
    unsigned short* __restrict__ WoT, float* __restrict__ keys) {
    __shared__ float tile[32][33];
    prep_vb(blockIdx.x, Wq, Ws, Wo, WqT, WsT, WoT, keys, tile);
}

__global__ __launch_bounds__(256) void k_stageB(
    const float* __restrict__ query, const float* __restrict__ src,
    const float* __restrict__ trg, const unsigned short* __restrict__ WqT,
    const unsigned short* __restrict__ WsT, const unsigned short* __restrict__ WoT,
    const float* __restrict__ bq, const float* __restrict__ bo,
    unsigned short* __restrict__ qh, float* __restrict__ keys,
    float* __restrict__ out) {
    __shared__ __align__(16) unsigned short As[64 * 72];
    __shared__ __align__(16) unsigned short Bs[64 * 72];
    stageB_vb(blockIdx.x, query, src, trg, WqT, WsT, WoT, bq, bo, qh, keys,
              out, As, Bs);
}

__global__ __launch_bounds__(256) void k_stageC(
    const unsigned short* __restrict__ qh, const float* __restrict__ keys,
    const unsigned short* __restrict__ wotBot, float* __restrict__ sc,
    float* __restrict__ P) {
    __shared__ __align__(16) unsigned short As[64 * 72];
    __shared__ __align__(16) unsigned short Bs[64 * 72];
    stageC_vb(blockIdx.x, qh, keys, wotBot, sc, P, As, Bs);
}

__global__ __launch_bounds__(256) void k_stageD(
    const float* __restrict__ sc, const float* __restrict__ P,
    float* __restrict__ out) {
    __shared__ float wbuf[200 * 33];
    __shared__ float Bs[40 * 32];
    const int vb = blockIdx.x + blockIdx.y * 16 + blockIdx.z * 128;
    stageD_vb(vb, sc, P, out, wbuf, Bs);
}

// ---------------- launch ----------------------------------------------------

extern "C" void kernel_launch(void* const* d_in, const int* in_sizes, int n_in,
                              void* d_out, int out_size, void* d_ws, size_t ws_size,
                              hipStream_t stream) {
    const float* query = (const float*)d_in[0];
    const float* src   = (const float*)d_in[1];
    const float* trg   = (const float*)d_in[2];
    const float* Wq    = (const float*)d_in[3];
    const float* bq    = (const float*)d_in[4];
    const float* Ws    = (const float*)d_in[5];
    const float* Wo    = (const float*)d_in[7];
    const float* bo    = (const float*)d_in[8];
    float* out = (float*)d_out;

    float* keys = (float*)d_ws;               // 1600*512 fp32 (UNBIASED)
    float* sc   = keys + 819200;              // 1024*256 fp32
    float* P    = sc   + 262144;              // 1600*512 fp32 = keys @ WoBot
    unsigned short* qh  = (unsigned short*)(P + 819200);  // 1024x512 bf16
    unsigned short* wqt = qh  + 524288;       // WqT 512x512
    unsigned short* wst = wqt + 262144;       // WsT 512x2048
    unsigned short* wot = wst + 1048576;      // WoT 512x1024

    // ---- NB: runtime occupancy-derived grid size (cached). -1 => fallback.
    static int s_nb = 0;
    if (s_nb == 0) {
        int perCU = 0;
        hipError_t oe = hipOccupancyMaxActiveBlocksPerMultiprocessor(
            &perCU, k_fused, 256, 0);
        if (oe == hipSuccess && perCU > 0) {
            int nCU = 0;
            hipDeviceProp_t prop;
            if (hipGetDeviceProperties(&prop, 0) == hipSuccess)
                nCU = prop.multiProcessorCount;
            if (nCU <= 0) nCU = 256;
            long nb = (long)perCU * nCU;
            s_nb = (int)(nb > 768 ? 768 : nb);
            if (s_nb < 64) s_nb = -1;         // absurdly low -> don't bother
        } else {
            s_nb = -1;
        }
    }

    hipError_t le = hipErrorUnknown;
    if (s_nb > 0) {
        int nbv = s_nb;
        void* args[] = {
            (void*)&query, (void*)&src, (void*)&trg, (void*)&Wq, (void*)&bq,
            (void*)&Ws, (void*)&Wo, (void*)&bo, (void*)&wqt, (void*)&wst,
            (void*)&wot, (void*)&qh, (void*)&keys, (void*)&sc, (void*)&P,
            (void*)&out, (void*)&nbv};
        le = hipLaunchCooperativeKernel(k_fused, dim3(s_nb), dim3(256), args,
                                        0, stream);
        if (le != hipSuccess) s_nb = -1;      // permanently switch to fallback
    }
    if (le != hipSuccess) {
        // known-good 4-kernel pipeline
        k_prep<<<2592, 256, 0, stream>>>(Wq, Ws, Wo, wqt, wst, wot, keys);
        k_stageB<<<912, 256, 0, stream>>>(query, src, trg, wqt, wst, wot, bq,
                                          bo, qh, keys, out);
        k_stageC<<<328, 256, 0, stream>>>(qh, keys, wot + 512, sc, P);
        k_stageD<<<dim3(16, 8, 4), 256, 0, stream>>>(sc, P, out);
    }
}

// Round 4
// 134.547 us; speedup vs baseline: 4.3257x; 2.5283x over previous
//
#include <hip/hip_runtime.h>
#include <math.h>

// DynamicAttention1 — round 16: revert coop (8-XCD grid.sync floor ~170us+,
// R14/R15 A/B proved it), back to 4-kernel pipeline + shrink stage work:
//   - keys GEMM: split-K dropped (200 blocks x 32 iters, same total work,
//     all blocks co-resident) -> no atomics, no zero-init.
//   - keys stored bf16 directly (consumers already rounded via cvt8 ->
//     numerically identical); stageC inner loops now load s16x8 straight,
//     no fp32->bf16 convert, half the keys bytes.
//   - prep = 1792 transpose blocks only.
//   pipeline: prep(transposes) -> stageB(keys 200 + qh 256 + out_left 256)
//             -> stageC(scgemm 128 + Pgemm 200) -> stageD(softmax + wP -> out)
// keys stay UNBIASED everywhere: bs cancels in scores (difference) and in
// ctx (softmax weights sum to 1) — verified empirically in R9/R10.

typedef __attribute__((ext_vector_type(8))) short s16x8;
typedef __attribute__((ext_vector_type(4))) float f32x4;

__device__ __forceinline__ unsigned short f2bf(float f) {
    unsigned int u = __float_as_uint(f);
    return (unsigned short)((u + 0x7fffu + ((u >> 16) & 1u)) >> 16);  // RNE
}

__device__ __forceinline__ s16x8 cvt8(const float* p) {
    float4 u = *(const float4*)p, w = *(const float4*)(p + 4);
    s16x8 o;
    o[0] = (short)f2bf(u.x); o[1] = (short)f2bf(u.y);
    o[2] = (short)f2bf(u.z); o[3] = (short)f2bf(u.w);
    o[4] = (short)f2bf(w.x); o[5] = (short)f2bf(w.y);
    o[6] = (short)f2bf(w.z); o[7] = (short)f2bf(w.w);
    return o;
}

// ---------------- prep: weight transpose-casts ------------------------------
__global__ __launch_bounds__(256) void k_prep(
    const float* __restrict__ Wq, const float* __restrict__ Ws,
    const float* __restrict__ Wo,
    unsigned short* __restrict__ WqT, unsigned short* __restrict__ WsT,
    unsigned short* __restrict__ WoT) {
    __shared__ float tile[32][33];
    const int id = blockIdx.x, t = threadIdx.x;

    const float* W; unsigned short* O; int K, tk, tn;
    if (id < 256)       { W = Wq; O = WqT; K = 512;  tk = id >> 4;          tn = id & 15; }
    else if (id < 1280) { W = Ws; O = WsT; K = 2048; tk = (id - 256) >> 4;  tn = (id - 256) & 15; }
    else                { W = Wo; O = WoT; K = 1024; tk = (id - 1280) >> 4; tn = (id - 1280) & 15; }
    const int row = t >> 3, c4 = (t & 7) * 4;
    float4 v = *(const float4*)(W + (size_t)(tk * 32 + row) * 512 + tn * 32 + c4);
    tile[row][c4 + 0] = v.x; tile[row][c4 + 1] = v.y;
    tile[row][c4 + 2] = v.z; tile[row][c4 + 3] = v.w;
    __syncthreads();
    ushort4 o = make_ushort4(f2bf(tile[c4 + 0][row]), f2bf(tile[c4 + 1][row]),
                             f2bf(tile[c4 + 2][row]), f2bf(tile[c4 + 3][row]));
    *(ushort4*)(O + (size_t)(tn * 32 + row) * K + tk * 32 + c4) = o;
}

// ---------------- keys GEMM: A = [src;trg] fp32, full K, bf16 store ---------
// 64x64 tile, 4 waves 2x2; K=2048 (32 iters), direct bf16 epilogue.
__device__ __forceinline__ void gemm64_keys(
    const float* __restrict__ src, const float* __restrict__ trg,
    const unsigned short* __restrict__ BT, unsigned short* __restrict__ Kb,
    int m0, int n0, unsigned short* As, unsigned short* Bs) {
    const int t = threadIdx.x;
    const int lane = t & 63, wid = t >> 6;
    const int wm = (wid & 1) * 32, wn = (wid >> 1) * 32;
    const int lr = lane & 15, lq = lane >> 4;
    const int r = t >> 3, c8 = (t & 7) * 8;

    const int ra_row = m0 + r, rb_row = m0 + r + 32;
    const float* arp = (ra_row < 800) ? (src + (size_t)ra_row * 2048)
                                      : (trg + (size_t)(ra_row - 800) * 2048);
    const float* brp = (rb_row < 800) ? (src + (size_t)rb_row * 2048)
                                      : (trg + (size_t)(rb_row - 800) * 2048);

    s16x8 ra0, ra1, rb0, rb1;
#define LDK(kt)                                                            \
    ra0 = cvt8(arp + (kt) + c8);                                           \
    ra1 = cvt8(brp + (kt) + c8);                                           \
    rb0 = *(const s16x8*)(BT + (size_t)(n0 + r)      * 2048 + (kt) + c8);  \
    rb1 = *(const s16x8*)(BT + (size_t)(n0 + r + 32) * 2048 + (kt) + c8);

    f32x4 acc[2][2] = {};
    LDK(0);
    for (int it = 0; it < 32; it++) {
        __syncthreads();
        *(s16x8*)&As[r * 72 + c8]        = ra0;
        *(s16x8*)&As[(r + 32) * 72 + c8] = ra1;
        *(s16x8*)&Bs[r * 72 + c8]        = rb0;
        *(s16x8*)&Bs[(r + 32) * 72 + c8] = rb1;
        __syncthreads();
        if (it < 31) { LDK((it + 1) * 64); }  // prefetch
#pragma unroll
        for (int s = 0; s < 2; s++) {
            s16x8 a0 = *(const s16x8*)&As[(wm + lr) * 72      + s * 32 + lq * 8];
            s16x8 a1 = *(const s16x8*)&As[(wm + 16 + lr) * 72 + s * 32 + lq * 8];
            s16x8 b0 = *(const s16x8*)&Bs[(wn + lr) * 72      + s * 32 + lq * 8];
            s16x8 b1 = *(const s16x8*)&Bs[(wn + 16 + lr) * 72 + s * 32 + lq * 8];
            acc[0][0] = __builtin_amdgcn_mfma_f32_16x16x32_bf16(a0, b0, acc[0][0], 0, 0, 0);
            acc[0][1] = __builtin_amdgcn_mfma_f32_16x16x32_bf16(a0, b1, acc[0][1], 0, 0, 0);
            acc[1][0] = __builtin_amdgcn_mfma_f32_16x16x32_bf16(a1, b0, acc[1][0], 0, 0, 0);
            acc[1][1] = __builtin_amdgcn_mfma_f32_16x16x32_bf16(a1, b1, acc[1][1], 0, 0, 0);
        }
    }
#undef LDK
#pragma unroll
    for (int i = 0; i < 2; i++)
#pragma unroll
        for (int j = 0; j < 2; j++) {
            const int col = n0 + wn + j * 16 + lr;      // C/D: col=lane&15
            const int row = m0 + wm + i * 16 + lq * 4;  //      row=quad*4+reg
#pragma unroll
            for (int rr = 0; rr < 4; rr++)
                Kb[(size_t)(row + rr) * 512 + col] = f2bf(acc[i][j][rr]);
        }
}

// ---------------- P GEMM: P = keys(bf16) @ WoBot (direct fp32 store) --------
// 64x64 tile, 4 waves 2x2, K=512 (8 iters).
__device__ __forceinline__ void gemm64_P(
    const unsigned short* __restrict__ Kb, const unsigned short* __restrict__ wotBot,
    float* __restrict__ P, int m0, int n0, unsigned short* As,
    unsigned short* Bs) {
    const int t = threadIdx.x;
    const int lane = t & 63, wid = t >> 6;
    const int wm = (wid & 1) * 32, wn = (wid >> 1) * 32;
    const int lr = lane & 15, lq = lane >> 4;
    const int r = t >> 3, c8 = (t & 7) * 8;

    s16x8 ra0, ra1, rb0, rb1;
#define LDP(kt)                                                               \
    ra0 = *(const s16x8*)(Kb + (size_t)(m0 + r)      * 512 + (kt) + c8);      \
    ra1 = *(const s16x8*)(Kb + (size_t)(m0 + r + 32) * 512 + (kt) + c8);      \
    rb0 = *(const s16x8*)(wotBot + (size_t)(n0 + r)      * 1024 + (kt) + c8); \
    rb1 = *(const s16x8*)(wotBot + (size_t)(n0 + r + 32) * 1024 + (kt) + c8);

    f32x4 acc[2][2] = {};
    LDP(0);
    for (int it = 0; it < 8; it++) {
        __syncthreads();
        *(s16x8*)&As[r * 72 + c8]        = ra0;
        *(s16x8*)&As[(r + 32) * 72 + c8] = ra1;
        *(s16x8*)&Bs[r * 72 + c8]        = rb0;
        *(s16x8*)&Bs[(r + 32) * 72 + c8] = rb1;
        __syncthreads();
        if (it < 7) { LDP((it + 1) * 64); }  // prefetch
#pragma unroll
        for (int s = 0; s < 2; s++) {
            s16x8 a0 = *(const s16x8*)&As[(wm + lr) * 72      + s * 32 + lq * 8];
            s16x8 a1 = *(const s16x8*)&As[(wm + 16 + lr) * 72 + s * 32 + lq * 8];
            s16x8 b0 = *(const s16x8*)&Bs[(wn + lr) * 72      + s * 32 + lq * 8];
            s16x8 b1 = *(const s16x8*)&Bs[(wn + 16 + lr) * 72 + s * 32 + lq * 8];
            acc[0][0] = __builtin_amdgcn_mfma_f32_16x16x32_bf16(a0, b0, acc[0][0], 0, 0, 0);
            acc[0][1] = __builtin_amdgcn_mfma_f32_16x16x32_bf16(a0, b1, acc[0][1], 0, 0, 0);
            acc[1][0] = __builtin_amdgcn_mfma_f32_16x16x32_bf16(a1, b0, acc[1][0], 0, 0, 0);
            acc[1][1] = __builtin_amdgcn_mfma_f32_16x16x32_bf16(a1, b1, acc[1][1], 0, 0, 0);
        }
    }
#undef LDP
#pragma unroll
    for (int i = 0; i < 2; i++)
#pragma unroll
        for (int j = 0; j < 2; j++) {
            const int col = n0 + wn + j * 16 + lr;
            const int row = m0 + wm + i * 16 + lq * 4;
#pragma unroll
            for (int rr = 0; rr < 4; rr++)
                P[(size_t)(row + rr) * 512 + col] = acc[i][j][rr];
        }
}

// 32x64 tile, 4 waves. A fp32 (cvt in staging). MODE 0: fp32+bias,
// 2: bf16+bias.
template <int MODE>
__device__ __forceinline__ void gemm32(
    const float* __restrict__ A, const unsigned short* __restrict__ BT,
    const float* __restrict__ bias, void* __restrict__ Cv,
    int m0, int n0, int KA, int KB, int N, int kiters,
    unsigned short* As, unsigned short* Bs) {
    const int t = threadIdx.x;
    const int lane = t & 63, wid = t >> 6;
    const int wm = (wid & 1) * 16, wn = (wid >> 1) * 32;
    const int lr = lane & 15, lq = lane >> 4;
    const int r = t >> 3, c8 = (t & 7) * 8;

    s16x8 ra, rb0, rb1;
#define LD32(kt)                                                            \
    ra  = cvt8(A + (size_t)(m0 + r) * KA + (kt) + c8);                      \
    rb0 = *(const s16x8*)(BT + (size_t)(n0 + r)      * KB + (kt) + c8);     \
    rb1 = *(const s16x8*)(BT + (size_t)(n0 + r + 32) * KB + (kt) + c8);

    f32x4 acc[2] = {};
    LD32(0);
    for (int it = 0; it < kiters; it++) {
        __syncthreads();
        *(s16x8*)&As[r * 72 + c8]        = ra;
        *(s16x8*)&Bs[r * 72 + c8]        = rb0;
        *(s16x8*)&Bs[(r + 32) * 72 + c8] = rb1;
        __syncthreads();
        if (it + 1 < kiters) { LD32((it + 1) * 64); }  // prefetch
#pragma unroll
        for (int s = 0; s < 2; s++) {
            s16x8 a0 = *(const s16x8*)&As[(wm + lr) * 72      + s * 32 + lq * 8];
            s16x8 b0 = *(const s16x8*)&Bs[(wn + lr) * 72      + s * 32 + lq * 8];
            s16x8 b1 = *(const s16x8*)&Bs[(wn + 16 + lr) * 72 + s * 32 + lq * 8];
            acc[0] = __builtin_amdgcn_mfma_f32_16x16x32_bf16(a0, b0, acc[0], 0, 0, 0);
            acc[1] = __builtin_amdgcn_mfma_f32_16x16x32_bf16(a0, b1, acc[1], 0, 0, 0);
        }
    }
#undef LD32
#pragma unroll
    for (int j = 0; j < 2; j++) {
        const int col = n0 + wn + j * 16 + lr;
        const int row = m0 + wm + lq * 4;
        const float bv = bias[col];
        if (MODE == 0) {
            float* C = (float*)Cv;
#pragma unroll
            for (int rr = 0; rr < 4; rr++)
                C[(size_t)(row + rr) * N + col] = acc[j][rr] + bv;
        } else {
            unsigned short* C = (unsigned short*)Cv;
#pragma unroll
            for (int rr = 0; rr < 4; rr++)
                C[(size_t)(row + rr) * N + col] = f2bf(acc[j][rr] + bv);
        }
    }
}

// ---------------- stage B: keys (200) + qh (256) + out_left (256) -----------
__global__ __launch_bounds__(256) void k_stageB(
    const float* __restrict__ query, const float* __restrict__ src,
    const float* __restrict__ trg, const unsigned short* __restrict__ WqT,
    const unsigned short* __restrict__ WsT, const unsigned short* __restrict__ WoT,
    const float* __restrict__ bq, const float* __restrict__ bo,
    unsigned short* __restrict__ qh, unsigned short* __restrict__ keysbf,
    float* __restrict__ out) {
    __shared__ __align__(16) unsigned short As[64 * 72];
    __shared__ __align__(16) unsigned short Bs[64 * 72];
    const int bid = blockIdx.x;
    if (bid < 200) {
        gemm64_keys(src, trg, WsT, keysbf, (bid >> 3) * 64, (bid & 7) * 64,
                    As, Bs);
    } else if (bid < 456) {
        const int r = bid - 200;
        gemm32<2>(query, WqT, bq, qh, (r >> 3) * 32, (r & 7) * 64, 512, 512,
                  512, 8, As, Bs);
    } else {
        const int r = bid - 456;
        gemm32<0>(query, WoT, bo, out, (r >> 3) * 32, (r & 7) * 64, 512, 1024,
                  512, 8, As, Bs);
    }
}

// ---------------- stage C: scgemm (128 blocks) + Pgemm (200 blocks) ---------
// scgemm: sc[b*128+l][n], cols 0..99 = qs/32, cols 128..227 = -qt/32.
__global__ __launch_bounds__(256) void k_stageC(
    const unsigned short* __restrict__ qh, const unsigned short* __restrict__ keysbf,
    const unsigned short* __restrict__ wotBot, float* __restrict__ sc,
    float* __restrict__ P) {
    __shared__ __align__(16) unsigned short As[64 * 72];
    __shared__ __align__(16) unsigned short Bs[64 * 72];
    const int bid = blockIdx.x;
    const int t = threadIdx.x;

    if (bid >= 128) {                       // ---- Pgemm ----
        const int rem = bid - 128;
        gemm64_P(keysbf, wotBot, P, (rem >> 3) * 64, (rem & 7) * 64, As, Bs);
        return;
    }

    // ---- scgemm ----
    const int mt = bid >> 2, nt = bid & 3;
    const int m0 = mt * 32, b = mt >> 2, n0 = nt * 64;
    const int lane = t & 63, wid = t >> 6;
    const int wm = (wid & 1) * 16, wn = (wid >> 1) * 32;
    const int lr = lane & 15, lq = lane >> 4;
    const int r = t >> 3, c8 = (t & 7) * 8;

    const int nA = n0 + r, nB = n0 + r + 32;
    int kr0 = (nA < 128) ? (b * 100 + nA) : (800 + b * 100 + (nA - 128));
    int kr1 = (nB < 128) ? (b * 100 + nB) : (800 + b * 100 + (nB - 128));
    kr0 = kr0 > 1599 ? 1599 : kr0;
    kr1 = kr1 > 1599 ? 1599 : kr1;

    s16x8 ra, rb0, rb1;
#define LDSC(kt)                                                        \
    ra  = *(const s16x8*)(qh + (size_t)(m0 + r) * 512 + (kt) + c8);     \
    rb0 = *(const s16x8*)(keysbf + (size_t)kr0 * 512 + (kt) + c8);      \
    rb1 = *(const s16x8*)(keysbf + (size_t)kr1 * 512 + (kt) + c8);

    f32x4 acc[2] = {};
    LDSC(0);
    for (int it = 0; it < 8; it++) {
        __syncthreads();
        *(s16x8*)&As[r * 72 + c8]        = ra;
        *(s16x8*)&Bs[r * 72 + c8]        = rb0;
        *(s16x8*)&Bs[(r + 32) * 72 + c8] = rb1;
        __syncthreads();
        if (it < 7) { LDSC((it + 1) * 64); }
#pragma unroll
        for (int s = 0; s < 2; s++) {
            s16x8 a0 = *(const s16x8*)&As[(wm + lr) * 72      + s * 32 + lq * 8];
            s16x8 b0 = *(const s16x8*)&Bs[(wn + lr) * 72      + s * 32 + lq * 8];
            s16x8 b1 = *(const s16x8*)&Bs[(wn + 16 + lr) * 72 + s * 32 + lq * 8];
            acc[0] = __builtin_amdgcn_mfma_f32_16x16x32_bf16(a0, b0, acc[0], 0, 0, 0);
            acc[1] = __builtin_amdgcn_mfma_f32_16x16x32_bf16(a0, b1, acc[1], 0, 0, 0);
        }
    }
#undef LDSC
#pragma unroll
    for (int j = 0; j < 2; j++) {
        const int col = n0 + wn + j * 16 + lr;
        const int row = m0 + wm + lq * 4;
        const float scale = (col >= 128) ? -(1.0f / 32.0f) : (1.0f / 32.0f);
#pragma unroll
        for (int rr = 0; rr < 4; rr++)
            sc[(size_t)(row + rr) * 256 + col] = acc[j][rr] * scale;
    }
}

// ---------------- stage D: softmax + wP GEMM -> atomic into out -------------
// grid (16 n-tiles, 8 b, 4 l-tiles) = 512 blocks of 32(l) x 32(n), K=200.
__global__ __launch_bounds__(256) void k_stageD(
    const float* __restrict__ sc, const float* __restrict__ P,
    float* __restrict__ out) {
    __shared__ float wbuf[200 * 33];     // [st][l], pad 33
    __shared__ float Bs[40 * 32];        // [k][n]

    const int t = threadIdx.x;
    const int b = blockIdx.y;
    const int n0 = blockIdx.x * 32;
    const int l0 = blockIdx.z * 32;
    const int wave = t >> 6, lane = t & 63;

    // ---- softmax: each wave handles 8 rows; lane covers cols lane*4..+3 ----
    for (int i = 0; i < 8; i++) {
        const int li = wave * 8 + i;                  // 0..31
        const float4 v = *(const float4*)(
            sc + (size_t)(b * 128 + l0 + li) * 256 + lane * 4);
        const float vv[4] = {v.x, v.y, v.z, v.w};
        const int c0 = lane * 4;
        float mS = -1e30f, mT = -1e30f;
#pragma unroll
        for (int j = 0; j < 4; j++) {
            const int col = c0 + j;
            if (col < 100) mS = fmaxf(mS, vv[j]);
            if (col >= 128 && col < 228) mT = fmaxf(mT, vv[j]);
        }
#pragma unroll
        for (int off = 32; off > 0; off >>= 1) {
            mS = fmaxf(mS, __shfl_xor(mS, off));
            mT = fmaxf(mT, __shfl_xor(mT, off));
        }
        float eS[4], eT[4], sS = 0.f, sT = 0.f;
#pragma unroll
        for (int j = 0; j < 4; j++) {
            const int col = c0 + j;
            eS[j] = (col < 100) ? __expf(vv[j] - mS) : 0.f;
            eT[j] = (col >= 128 && col < 228) ? __expf(vv[j] - mT) : 0.f;
            sS += eS[j]; sT += eT[j];
        }
#pragma unroll
        for (int off = 32; off > 0; off >>= 1) {
            sS += __shfl_xor(sS, off);
            sT += __shfl_xor(sT, off);
        }
        const float iS = 1.f / sS, iT = 1.f / sT;
#pragma unroll
        for (int j = 0; j < 4; j++) {
            const int col = c0 + j;
            if (col < 100) wbuf[col * 33 + li] = eS[j] * iS;
            if (col >= 128 && col < 228)
                wbuf[(100 + col - 128) * 33 + li] = eT[j] * iT;
        }
    }
    __syncthreads();

    // ---- GEMM: acc[l][n] += w[st][l] * (+P_s|-P_t)[st][n] ------------------
    const int tx = t & 7, ty = t >> 3;   // tx: n/4, ty: l
    float rB[5];
    auto loadB = [&](int kbase) {
#pragma unroll
        for (int e = 0; e < 5; e++) {
            const int idx = t + e * 256;
            const int k = idx >> 5, j = idx & 31;
            const int kk = kbase + k;
            rB[e] = (kk < 100)
                ?  P[(size_t)(b * 100 + kk) * 512 + n0 + j]
                : -P[(size_t)(800 + b * 100 + (kk - 100)) * 512 + n0 + j];
        }
    };

    float acc[4] = {};
    loadB(0);
    for (int c5 = 0; c5 < 5; c5++) {
        __syncthreads();
#pragma unroll
        for (int e = 0; e < 5; e++) {
            const int idx = t + e * 256;
            Bs[idx] = rB[e];
        }
        __syncthreads();
        if (c5 < 4) loadB((c5 + 1) * 40);          // prefetch next chunk
#pragma unroll 8
        for (int k = 0; k < 40; k++) {
            const float ar = wbuf[(c5 * 40 + k) * 33 + ty];
            float br[4];
            *(float4*)br = *(const float4*)&Bs[k * 32 + tx * 4];
#pragma unroll
            for (int j = 0; j < 4; j++) acc[j] = fmaf(ar, br[j], acc[j]);
        }
    }

    const float s2 = 0.70710678118654752f;  // 1/sqrt(2)
    const int m = b * 128 + l0 + ty;
#pragma unroll
    for (int j = 0; j < 4; j++)
        unsafeAtomicAdd(&out[(size_t)m * 512 + n0 + tx * 4 + j], acc[j] * s2);
}

// ---------------- launch ----------------------------------------------------

extern "C" void kernel_launch(void* const* d_in, const int* in_sizes, int n_in,
                              void* d_out, int out_size, void* d_ws, size_t ws_size,
                              hipStream_t stream) {
    const float* query = (const float*)d_in[0];
    const float* src   = (const float*)d_in[1];
    const float* trg   = (const float*)d_in[2];
    const float* Wq    = (const float*)d_in[3];
    const float* bq    = (const float*)d_in[4];
    const float* Ws    = (const float*)d_in[5];
    const float* Wo    = (const float*)d_in[7];
    const float* bo    = (const float*)d_in[8];
    float* out = (float*)d_out;

    // workspace layout (16B-aligned chunks)
    unsigned short* keysbf = (unsigned short*)d_ws;      // 1600x512 bf16
    float* sc = (float*)(keysbf + 819200);               // 1024x256 fp32
    float* P  = sc + 262144;                             // 1600x512 fp32
    unsigned short* qh  = (unsigned short*)(P + 819200); // 1024x512 bf16
    unsigned short* wqt = qh  + 524288;                  // WqT 512x512
    unsigned short* wst = wqt + 262144;                  // WsT 512x2048
    unsigned short* wot = wst + 1048576;                 // WoT 512x1024

    k_prep<<<1792, 256, 0, stream>>>(Wq, Ws, Wo, wqt, wst, wot);
    k_stageB<<<712, 256, 0, stream>>>(query, src, trg, wqt, wst, wot, bq, bo,
                                      qh, keysbf, out);
    k_stageC<<<328, 256, 0, stream>>>(qh, keysbf, wot + 512, sc, P);
    k_stageD<<<dim3(16, 8, 4), 256, 0, stream>>>(sc, P, out);
}

// Round 5
// 133.365 us; speedup vs baseline: 4.3640x; 1.0089x over previous
//
#include <hip/hip_runtime.h>
#include <math.h>

// DynamicAttention1 — round 17: pre-convert A-matrices to bf16, kill in-loop cvt.
// R16 (full-K keys, bf16 keys store) = 134.5us vs R12 129.6: the 32-iter keys
// path is VALU-bound — 2x cvt8 per iter = ~128 VALU ops/thread (~256 cy/wave),
// dwarfing the 8 MFMAs. Fix: prep converts query/src/trg -> bf16 ONCE (1856
// extra one-shot blocks, ~3us); every GEMM A-load becomes a direct s16x8 load
// (zero inner-loop VALU convert) and A traffic halves (8x re-read was fp32).
// Numerically identical: cvt8 applied the same RNE rounding per use.
//   pipeline: prep(transposes 1792 + converts 1856)
//             -> stageB(keys 200 x 32it + qh 256 + out_left 256)
//             -> stageC(scgemm 128 + Pgemm 200) -> stageD(softmax + wP -> out)
// keys UNBIASED everywhere: bs cancels in scores (difference) and in ctx
// (softmax weights sum to 1) — verified R9/R10.

typedef __attribute__((ext_vector_type(8))) short s16x8;
typedef __attribute__((ext_vector_type(4))) float f32x4;

__device__ __forceinline__ unsigned short f2bf(float f) {
    unsigned int u = __float_as_uint(f);
    return (unsigned short)((u + 0x7fffu + ((u >> 16) & 1u)) >> 16);  // RNE
}

__device__ __forceinline__ s16x8 cvt8(const float* p) {
    float4 u = *(const float4*)p, w = *(const float4*)(p + 4);
    s16x8 o;
    o[0] = (short)f2bf(u.x); o[1] = (short)f2bf(u.y);
    o[2] = (short)f2bf(u.z); o[3] = (short)f2bf(u.w);
    o[4] = (short)f2bf(w.x); o[5] = (short)f2bf(w.y);
    o[6] = (short)f2bf(w.z); o[7] = (short)f2bf(w.w);
    return o;
}

// ---------------- prep: weight transpose-casts + activation bf16 casts ------
__global__ __launch_bounds__(256) void k_prep(
    const float* __restrict__ Wq, const float* __restrict__ Ws,
    const float* __restrict__ Wo, const float* __restrict__ query,
    const float* __restrict__ src, const float* __restrict__ trg,
    unsigned short* __restrict__ WqT, unsigned short* __restrict__ WsT,
    unsigned short* __restrict__ WoT, unsigned short* __restrict__ qbf,
    unsigned short* __restrict__ srcbf, unsigned short* __restrict__ trgbf) {
    __shared__ float tile[32][33];
    const int id = blockIdx.x, t = threadIdx.x;

    if (id < 1792) {                        // weight transpose-cast, 32x32 tiles
        const float* W; unsigned short* O; int K, tk, tn;
        if (id < 256)       { W = Wq; O = WqT; K = 512;  tk = id >> 4;          tn = id & 15; }
        else if (id < 1280) { W = Ws; O = WsT; K = 2048; tk = (id - 256) >> 4;  tn = (id - 256) & 15; }
        else                { W = Wo; O = WoT; K = 1024; tk = (id - 1280) >> 4; tn = (id - 1280) & 15; }
        const int row = t >> 3, c4 = (t & 7) * 4;
        float4 v = *(const float4*)(W + (size_t)(tk * 32 + row) * 512 + tn * 32 + c4);
        tile[row][c4 + 0] = v.x; tile[row][c4 + 1] = v.y;
        tile[row][c4 + 2] = v.z; tile[row][c4 + 3] = v.w;
        __syncthreads();
        ushort4 o = make_ushort4(f2bf(tile[c4 + 0][row]), f2bf(tile[c4 + 1][row]),
                                 f2bf(tile[c4 + 2][row]), f2bf(tile[c4 + 3][row]));
        *(ushort4*)(O + (size_t)(tn * 32 + row) * K + tk * 32 + c4) = o;
    } else {                                // fp32 -> bf16 straight casts
        const int cid = id - 1792;
        const float* S; unsigned short* D; int base;
        if (cid < 256)       { S = query; D = qbf;   base = cid * 2048; }
        else if (cid < 1056) { S = src;   D = srcbf; base = (cid - 256) * 2048; }
        else                 { S = trg;   D = trgbf; base = (cid - 1056) * 2048; }
        const int off = base + t * 8;
        *(s16x8*)(D + off) = cvt8(S + off);
    }
}

// ---------------- keys GEMM: A = [src;trg] bf16, full K, bf16 store ---------
// 64x64 tile, 4 waves 2x2; K=2048 (32 iters), direct bf16 epilogue.
__device__ __forceinline__ void gemm64_keys(
    const unsigned short* __restrict__ srcbf, const unsigned short* __restrict__ trgbf,
    const unsigned short* __restrict__ BT, unsigned short* __restrict__ Kb,
    int m0, int n0, unsigned short* As, unsigned short* Bs) {
    const int t = threadIdx.x;
    const int lane = t & 63, wid = t >> 6;
    const int wm = (wid & 1) * 32, wn = (wid >> 1) * 32;
    const int lr = lane & 15, lq = lane >> 4;
    const int r = t >> 3, c8 = (t & 7) * 8;

    const int ra_row = m0 + r, rb_row = m0 + r + 32;
    const unsigned short* arp = (ra_row < 800)
        ? (srcbf + (size_t)ra_row * 2048) : (trgbf + (size_t)(ra_row - 800) * 2048);
    const unsigned short* brp = (rb_row < 800)
        ? (srcbf + (size_t)rb_row * 2048) : (trgbf + (size_t)(rb_row - 800) * 2048);

    s16x8 ra0, ra1, rb0, rb1;
#define LDK(kt)                                                            \
    ra0 = *(const s16x8*)(arp + (kt) + c8);                                \
    ra1 = *(const s16x8*)(brp + (kt) + c8);                                \
    rb0 = *(const s16x8*)(BT + (size_t)(n0 + r)      * 2048 + (kt) + c8);  \
    rb1 = *(const s16x8*)(BT + (size_t)(n0 + r + 32) * 2048 + (kt) + c8);

    f32x4 acc[2][2] = {};
    LDK(0);
    for (int it = 0; it < 32; it++) {
        __syncthreads();
        *(s16x8*)&As[r * 72 + c8]        = ra0;
        *(s16x8*)&As[(r + 32) * 72 + c8] = ra1;
        *(s16x8*)&Bs[r * 72 + c8]        = rb0;
        *(s16x8*)&Bs[(r + 32) * 72 + c8] = rb1;
        __syncthreads();
        if (it < 31) { LDK((it + 1) * 64); }  // prefetch
#pragma unroll
        for (int s = 0; s < 2; s++) {
            s16x8 a0 = *(const s16x8*)&As[(wm + lr) * 72      + s * 32 + lq * 8];
            s16x8 a1 = *(const s16x8*)&As[(wm + 16 + lr) * 72 + s * 32 + lq * 8];
            s16x8 b0 = *(const s16x8*)&Bs[(wn + lr) * 72      + s * 32 + lq * 8];
            s16x8 b1 = *(const s16x8*)&Bs[(wn + 16 + lr) * 72 + s * 32 + lq * 8];
            acc[0][0] = __builtin_amdgcn_mfma_f32_16x16x32_bf16(a0, b0, acc[0][0], 0, 0, 0);
            acc[0][1] = __builtin_amdgcn_mfma_f32_16x16x32_bf16(a0, b1, acc[0][1], 0, 0, 0);
            acc[1][0] = __builtin_amdgcn_mfma_f32_16x16x32_bf16(a1, b0, acc[1][0], 0, 0, 0);
            acc[1][1] = __builtin_amdgcn_mfma_f32_16x16x32_bf16(a1, b1, acc[1][1], 0, 0, 0);
        }
    }
#undef LDK
#pragma unroll
    for (int i = 0; i < 2; i++)
#pragma unroll
        for (int j = 0; j < 2; j++) {
            const int col = n0 + wn + j * 16 + lr;      // C/D: col=lane&15
            const int row = m0 + wm + i * 16 + lq * 4;  //      row=quad*4+reg
#pragma unroll
            for (int rr = 0; rr < 4; rr++)
                Kb[(size_t)(row + rr) * 512 + col] = f2bf(acc[i][j][rr]);
        }
}

// ---------------- P GEMM: P = keys(bf16) @ WoBot (direct fp32 store) --------
// 64x64 tile, 4 waves 2x2, K=512 (8 iters).
__device__ __forceinline__ void gemm64_P(
    const unsigned short* __restrict__ Kb, const unsigned short* __restrict__ wotBot,
    float* __restrict__ P, int m0, int n0, unsigned short* As,
    unsigned short* Bs) {
    const int t = threadIdx.x;
    const int lane = t & 63, wid = t >> 6;
    const int wm = (wid & 1) * 32, wn = (wid >> 1) * 32;
    const int lr = lane & 15, lq = lane >> 4;
    const int r = t >> 3, c8 = (t & 7) * 8;

    s16x8 ra0, ra1, rb0, rb1;
#define LDP(kt)                                                               \
    ra0 = *(const s16x8*)(Kb + (size_t)(m0 + r)      * 512 + (kt) + c8);      \
    ra1 = *(const s16x8*)(Kb + (size_t)(m0 + r + 32) * 512 + (kt) + c8);      \
    rb0 = *(const s16x8*)(wotBot + (size_t)(n0 + r)      * 1024 + (kt) + c8); \
    rb1 = *(const s16x8*)(wotBot + (size_t)(n0 + r + 32) * 1024 + (kt) + c8);

    f32x4 acc[2][2] = {};
    LDP(0);
    for (int it = 0; it < 8; it++) {
        __syncthreads();
        *(s16x8*)&As[r * 72 + c8]        = ra0;
        *(s16x8*)&As[(r + 32) * 72 + c8] = ra1;
        *(s16x8*)&Bs[r * 72 + c8]        = rb0;
        *(s16x8*)&Bs[(r + 32) * 72 + c8] = rb1;
        __syncthreads();
        if (it < 7) { LDP((it + 1) * 64); }  // prefetch
#pragma unroll
        for (int s = 0; s < 2; s++) {
            s16x8 a0 = *(const s16x8*)&As[(wm + lr) * 72      + s * 32 + lq * 8];
            s16x8 a1 = *(const s16x8*)&As[(wm + 16 + lr) * 72 + s * 32 + lq * 8];
            s16x8 b0 = *(const s16x8*)&Bs[(wn + lr) * 72      + s * 32 + lq * 8];
            s16x8 b1 = *(const s16x8*)&Bs[(wn + 16 + lr) * 72 + s * 32 + lq * 8];
            acc[0][0] = __builtin_amdgcn_mfma_f32_16x16x32_bf16(a0, b0, acc[0][0], 0, 0, 0);
            acc[0][1] = __builtin_amdgcn_mfma_f32_16x16x32_bf16(a0, b1, acc[0][1], 0, 0, 0);
            acc[1][0] = __builtin_amdgcn_mfma_f32_16x16x32_bf16(a1, b0, acc[1][0], 0, 0, 0);
            acc[1][1] = __builtin_amdgcn_mfma_f32_16x16x32_bf16(a1, b1, acc[1][1], 0, 0, 0);
        }
    }
#undef LDP
#pragma unroll
    for (int i = 0; i < 2; i++)
#pragma unroll
        for (int j = 0; j < 2; j++) {
            const int col = n0 + wn + j * 16 + lr;
            const int row = m0 + wm + i * 16 + lq * 4;
#pragma unroll
            for (int rr = 0; rr < 4; rr++)
                P[(size_t)(row + rr) * 512 + col] = acc[i][j][rr];
        }
}

// 32x64 tile, 4 waves. A bf16 (pre-converted). MODE 0: fp32+bias, 2: bf16+bias.
template <int MODE>
__device__ __forceinline__ void gemm32(
    const unsigned short* __restrict__ A, const unsigned short* __restrict__ BT,
    const float* __restrict__ bias, void* __restrict__ Cv,
    int m0, int n0, int KA, int KB, int N, int kiters,
    unsigned short* As, unsigned short* Bs) {
    const int t = threadIdx.x;
    const int lane = t & 63, wid = t >> 6;
    const int wm = (wid & 1) * 16, wn = (wid >> 1) * 32;
    const int lr = lane & 15, lq = lane >> 4;
    const int r = t >> 3, c8 = (t & 7) * 8;

    s16x8 ra, rb0, rb1;
#define LD32(kt)                                                            \
    ra  = *(const s16x8*)(A + (size_t)(m0 + r) * KA + (kt) + c8);           \
    rb0 = *(const s16x8*)(BT + (size_t)(n0 + r)      * KB + (kt) + c8);     \
    rb1 = *(const s16x8*)(BT + (size_t)(n0 + r + 32) * KB + (kt) + c8);

    f32x4 acc[2] = {};
    LD32(0);
    for (int it = 0; it < kiters; it++) {
        __syncthreads();
        *(s16x8*)&As[r * 72 + c8]        = ra;
        *(s16x8*)&Bs[r * 72 + c8]        = rb0;
        *(s16x8*)&Bs[(r + 32) * 72 + c8] = rb1;
        __syncthreads();
        if (it + 1 < kiters) { LD32((it + 1) * 64); }  // prefetch
#pragma unroll
        for (int s = 0; s < 2; s++) {
            s16x8 a0 = *(const s16x8*)&As[(wm + lr) * 72      + s * 32 + lq * 8];
            s16x8 b0 = *(const s16x8*)&Bs[(wn + lr) * 72      + s * 32 + lq * 8];
            s16x8 b1 = *(const s16x8*)&Bs[(wn + 16 + lr) * 72 + s * 32 + lq * 8];
            acc[0] = __builtin_amdgcn_mfma_f32_16x16x32_bf16(a0, b0, acc[0], 0, 0, 0);
            acc[1] = __builtin_amdgcn_mfma_f32_16x16x32_bf16(a0, b1, acc[1], 0, 0, 0);
        }
    }
#undef LD32
#pragma unroll
    for (int j = 0; j < 2; j++) {
        const int col = n0 + wn + j * 16 + lr;
        const int row = m0 + wm + lq * 4;
        const float bv = bias[col];
        if (MODE == 0) {
            float* C = (float*)Cv;
#pragma unroll
            for (int rr = 0; rr < 4; rr++)
                C[(size_t)(row + rr) * N + col] = acc[j][rr] + bv;
        } else {
            unsigned short* C = (unsigned short*)Cv;
#pragma unroll
            for (int rr = 0; rr < 4; rr++)
                C[(size_t)(row + rr) * N + col] = f2bf(acc[j][rr] + bv);
        }
    }
}

// ---------------- stage B: keys (200) + qh (256) + out_left (256) -----------
__global__ __launch_bounds__(256) void k_stageB(
    const unsigned short* __restrict__ qbf, const unsigned short* __restrict__ srcbf,
    const unsigned short* __restrict__ trgbf, const unsigned short* __restrict__ WqT,
    const unsigned short* __restrict__ WsT, const unsigned short* __restrict__ WoT,
    const float* __restrict__ bq, const float* __restrict__ bo,
    unsigned short* __restrict__ qh, unsigned short* __restrict__ keysbf,
    float* __restrict__ out) {
    __shared__ __align__(16) unsigned short As[64 * 72];
    __shared__ __align__(16) unsigned short Bs[64 * 72];
    const int bid = blockIdx.x;
    if (bid < 200) {
        gemm64_keys(srcbf, trgbf, WsT, keysbf, (bid >> 3) * 64, (bid & 7) * 64,
                    As, Bs);
    } else if (bid < 456) {
        const int r = bid - 200;
        gemm32<2>(qbf, WqT, bq, qh, (r >> 3) * 32, (r & 7) * 64, 512, 512,
                  512, 8, As, Bs);
    } else {
        const int r = bid - 456;
        gemm32<0>(qbf, WoT, bo, out, (r >> 3) * 32, (r & 7) * 64, 512, 1024,
                  512, 8, As, Bs);
    }
}

// ---------------- stage C: scgemm (128 blocks) + Pgemm (200 blocks) ---------
// scgemm: sc[b*128+l][n], cols 0..99 = qs/32, cols 128..227 = -qt/32.
__global__ __launch_bounds__(256) void k_stageC(
    const unsigned short* __restrict__ qh, const unsigned short* __restrict__ keysbf,
    const unsigned short* __restrict__ wotBot, float* __restrict__ sc,
    float* __restrict__ P) {
    __shared__ __align__(16) unsigned short As[64 * 72];
    __shared__ __align__(16) unsigned short Bs[64 * 72];
    const int bid = blockIdx.x;
    const int t = threadIdx.x;

    if (bid >= 128) {                       // ---- Pgemm ----
        const int rem = bid - 128;
        gemm64_P(keysbf, wotBot, P, (rem >> 3) * 64, (rem & 7) * 64, As, Bs);
        return;
    }

    // ---- scgemm ----
    const int mt = bid >> 2, nt = bid & 3;
    const int m0 = mt * 32, b = mt >> 2, n0 = nt * 64;
    const int lane = t & 63, wid = t >> 6;
    const int wm = (wid & 1) * 16, wn = (wid >> 1) * 32;
    const int lr = lane & 15, lq = lane >> 4;
    const int r = t >> 3, c8 = (t & 7) * 8;

    const int nA = n0 + r, nB = n0 + r + 32;
    int kr0 = (nA < 128) ? (b * 100 + nA) : (800 + b * 100 + (nA - 128));
    int kr1 = (nB < 128) ? (b * 100 + nB) : (800 + b * 100 + (nB - 128));
    kr0 = kr0 > 1599 ? 1599 : kr0;
    kr1 = kr1 > 1599 ? 1599 : kr1;

    s16x8 ra, rb0, rb1;
#define LDSC(kt)                                                        \
    ra  = *(const s16x8*)(qh + (size_t)(m0 + r) * 512 + (kt) + c8);     \
    rb0 = *(const s16x8*)(keysbf + (size_t)kr0 * 512 + (kt) + c8);      \
    rb1 = *(const s16x8*)(keysbf + (size_t)kr1 * 512 + (kt) + c8);

    f32x4 acc[2] = {};
    LDSC(0);
    for (int it = 0; it < 8; it++) {
        __syncthreads();
        *(s16x8*)&As[r * 72 + c8]        = ra;
        *(s16x8*)&Bs[r * 72 + c8]        = rb0;
        *(s16x8*)&Bs[(r + 32) * 72 + c8] = rb1;
        __syncthreads();
        if (it < 7) { LDSC((it + 1) * 64); }
#pragma unroll
        for (int s = 0; s < 2; s++) {
            s16x8 a0 = *(const s16x8*)&As[(wm + lr) * 72      + s * 32 + lq * 8];
            s16x8 b0 = *(const s16x8*)&Bs[(wn + lr) * 72      + s * 32 + lq * 8];
            s16x8 b1 = *(const s16x8*)&Bs[(wn + 16 + lr) * 72 + s * 32 + lq * 8];
            acc[0] = __builtin_amdgcn_mfma_f32_16x16x32_bf16(a0, b0, acc[0], 0, 0, 0);
            acc[1] = __builtin_amdgcn_mfma_f32_16x16x32_bf16(a0, b1, acc[1], 0, 0, 0);
        }
    }
#undef LDSC
#pragma unroll
    for (int j = 0; j < 2; j++) {
        const int col = n0 + wn + j * 16 + lr;
        const int row = m0 + wm + lq * 4;
        const float scale = (col >= 128) ? -(1.0f / 32.0f) : (1.0f / 32.0f);
#pragma unroll
        for (int rr = 0; rr < 4; rr++)
            sc[(size_t)(row + rr) * 256 + col] = acc[j][rr] * scale;
    }
}

// ---------------- stage D: softmax + wP GEMM -> atomic into out -------------
// grid (16 n-tiles, 8 b, 4 l-tiles) = 512 blocks of 32(l) x 32(n), K=200.
__global__ __launch_bounds__(256) void k_stageD(
    const float* __restrict__ sc, const float* __restrict__ P,
    float* __restrict__ out) {
    __shared__ float wbuf[200 * 33];     // [st][l], pad 33
    __shared__ float Bs[40 * 32];        // [k][n]

    const int t = threadIdx.x;
    const int b = blockIdx.y;
    const int n0 = blockIdx.x * 32;
    const int l0 = blockIdx.z * 32;
    const int wave = t >> 6, lane = t & 63;

    // ---- softmax: each wave handles 8 rows; lane covers cols lane*4..+3 ----
    for (int i = 0; i < 8; i++) {
        const int li = wave * 8 + i;                  // 0..31
        const float4 v = *(const float4*)(
            sc + (size_t)(b * 128 + l0 + li) * 256 + lane * 4);
        const float vv[4] = {v.x, v.y, v.z, v.w};
        const int c0 = lane * 4;
        float mS = -1e30f, mT = -1e30f;
#pragma unroll
        for (int j = 0; j < 4; j++) {
            const int col = c0 + j;
            if (col < 100) mS = fmaxf(mS, vv[j]);
            if (col >= 128 && col < 228) mT = fmaxf(mT, vv[j]);
        }
#pragma unroll
        for (int off = 32; off > 0; off >>= 1) {
            mS = fmaxf(mS, __shfl_xor(mS, off));
            mT = fmaxf(mT, __shfl_xor(mT, off));
        }
        float eS[4], eT[4], sS = 0.f, sT = 0.f;
#pragma unroll
        for (int j = 0; j < 4; j++) {
            const int col = c0 + j;
            eS[j] = (col < 100) ? __expf(vv[j] - mS) : 0.f;
            eT[j] = (col >= 128 && col < 228) ? __expf(vv[j] - mT) : 0.f;
            sS += eS[j]; sT += eT[j];
        }
#pragma unroll
        for (int off = 32; off > 0; off >>= 1) {
            sS += __shfl_xor(sS, off);
            sT += __shfl_xor(sT, off);
        }
        const float iS = 1.f / sS, iT = 1.f / sT;
#pragma unroll
        for (int j = 0; j < 4; j++) {
            const int col = c0 + j;
            if (col < 100) wbuf[col * 33 + li] = eS[j] * iS;
            if (col >= 128 && col < 228)
                wbuf[(100 + col - 128) * 33 + li] = eT[j] * iT;
        }
    }
    __syncthreads();

    // ---- GEMM: acc[l][n] += w[st][l] * (+P_s|-P_t)[st][n] ------------------
    const int tx = t & 7, ty = t >> 3;   // tx: n/4, ty: l
    float rB[5];
    auto loadB = [&](int kbase) {
#pragma unroll
        for (int e = 0; e < 5; e++) {
            const int idx = t + e * 256;
            const int k = idx >> 5, j = idx & 31;
            const int kk = kbase + k;
            rB[e] = (kk < 100)
                ?  P[(size_t)(b * 100 + kk) * 512 + n0 + j]
                : -P[(size_t)(800 + b * 100 + (kk - 100)) * 512 + n0 + j];
        }
    };

    float acc[4] = {};
    loadB(0);
    for (int c5 = 0; c5 < 5; c5++) {
        __syncthreads();
#pragma unroll
        for (int e = 0; e < 5; e++) {
            const int idx = t + e * 256;
            Bs[idx] = rB[e];
        }
        __syncthreads();
        if (c5 < 4) loadB((c5 + 1) * 40);          // prefetch next chunk
#pragma unroll 8
        for (int k = 0; k < 40; k++) {
            const float ar = wbuf[(c5 * 40 + k) * 33 + ty];
            float br[4];
            *(float4*)br = *(const float4*)&Bs[k * 32 + tx * 4];
#pragma unroll
            for (int j = 0; j < 4; j++) acc[j] = fmaf(ar, br[j], acc[j]);
        }
    }

    const float s2 = 0.70710678118654752f;  // 1/sqrt(2)
    const int m = b * 128 + l0 + ty;
#pragma unroll
    for (int j = 0; j < 4; j++)
        unsafeAtomicAdd(&out[(size_t)m * 512 + n0 + tx * 4 + j], acc[j] * s2);
}

// ---------------- launch ----------------------------------------------------

extern "C" void kernel_launch(void* const* d_in, const int* in_sizes, int n_in,
                              void* d_out, int out_size, void* d_ws, size_t ws_size,
                              hipStream_t stream) {
    const float* query = (const float*)d_in[0];
    const float* src   = (const float*)d_in[1];
    const float* trg   = (const float*)d_in[2];
    const float* Wq    = (const float*)d_in[3];
    const float* bq    = (const float*)d_in[4];
    const float* Ws    = (const float*)d_in[5];
    const float* Wo    = (const float*)d_in[7];
    const float* bo    = (const float*)d_in[8];
    float* out = (float*)d_out;

    // workspace layout (16B-aligned chunks)
    unsigned short* keysbf = (unsigned short*)d_ws;      // 1600x512 bf16
    float* sc = (float*)(keysbf + 819200);               // 1024x256 fp32
    float* P  = sc + 262144;                             // 1600x512 fp32
    unsigned short* qh  = (unsigned short*)(P + 819200); // 1024x512 bf16
    unsigned short* wqt = qh  + 524288;                  // WqT 512x512
    unsigned short* wst = wqt + 262144;                  // WsT 512x2048
    unsigned short* wot = wst + 1048576;                 // WoT 512x1024
    unsigned short* qbf   = wot + 524288;                // query bf16 1024x512
    unsigned short* srcbf = qbf + 524288;                // src bf16 800x2048
    unsigned short* trgbf = srcbf + 1638400;             // trg bf16 800x2048

    k_prep<<<3648, 256, 0, stream>>>(Wq, Ws, Wo, query, src, trg,
                                     wqt, wst, wot, qbf, srcbf, trgbf);
    k_stageB<<<712, 256, 0, stream>>>(qbf, srcbf, trgbf, wqt, wst, wot, bq, bo,
                                      qh, keysbf, out);
    k_stageC<<<328, 256, 0, stream>>>(qh, keysbf, wot + 512, sc, P);
    k_stageD<<<dim3(16, 8, 4), 256, 0, stream>>>(sc, P, out);
}